// Round 2
// 617.537 us; speedup vs baseline: 1.0739x; 1.0739x over previous
//
#include <hip/hip_runtime.h>
#include <hip/hip_bf16.h>
#include <hip/hip_fp16.h>

#define DEVINL __device__ __forceinline__

typedef float f32x4 __attribute__((ext_vector_type(4)));
typedef int i32x4 __attribute__((ext_vector_type(4)));
typedef unsigned int u32x4 __attribute__((ext_vector_type(4)));
typedef unsigned int u32x2 __attribute__((ext_vector_type(2)));

typedef __attribute__((address_space(1))) void void_g;
typedef __attribute__((address_space(3))) void void_l;

DEVINL void gload16(const void* g, void* l) {
  // async global->LDS, 16B/lane; LDS dst must be wave-uniform base + lane*16
  __builtin_amdgcn_global_load_lds((void_g*)g, (void_l*)l, 16, 0, 0);
}

DEVINL float wave_sum(float v) {
  #pragma unroll
  for (int o = 32; o > 0; o >>= 1) v += __shfl_down(v, o, 64);
  return v;
}
DEVINL float wave_max(float v) {
  #pragma unroll
  for (int o = 32; o > 0; o >>= 1) v = fmaxf(v, __shfl_down(v, o, 64));
  return v;
}

// pack 4 already-rounded-and-clamped floats into 4 signed bytes
DEVINL unsigned int pack4(float a, float b, float c, float d) {
  return ((unsigned int)(unsigned char)(signed char)(int)a)
       | (((unsigned int)(unsigned char)(signed char)(int)b) << 8)
       | (((unsigned int)(unsigned char)(signed char)(int)c) << 16)
       | (((unsigned int)(unsigned char)(signed char)(int)d) << 24);
}

// ---------------- sum(|w|) over fp32 tensor -> double ----------------
__global__ __launch_bounds__(256) void absum_kernel(const float* __restrict__ w,
                                                    long long nchunk, double* __restrict__ out) {
  long long stride = (long long)gridDim.x * 256;
  long long i = (long long)blockIdx.x * 256 + threadIdx.x;
  float s = 0.f;
  for (; i < nchunk; i += stride) {
    f32x4 v = ((const f32x4*)w)[i];
    s += fabsf(v[0]) + fabsf(v[1]) + fabsf(v[2]) + fabsf(v[3]);
  }
  s = wave_sum(s);
  __shared__ float red[4];
  int lane = threadIdx.x & 63, wv = threadIdx.x >> 6;
  if (lane == 0) red[wv] = s;
  __syncthreads();
  if (threadIdx.x == 0) atomicAdd(out, (double)(red[0] + red[1] + red[2] + red[3]));
}

// ---------------- ternary weight quant -> int8 {-1,0,1} ----------------
__global__ __launch_bounds__(256) void quantw_kernel(const float* __restrict__ w,
                                                     signed char* __restrict__ tern,
                                                     long long nchunk,  // groups of 8 floats
                                                     const double* __restrict__ sum, double inv_n) {
  float scale = (float)(1.0 / fmax(*sum * inv_n, 1e-5));
  long long stride = (long long)gridDim.x * 256;
  long long i = (long long)blockIdx.x * 256 + threadIdx.x;
  for (; i < nchunk; i += stride) {
    f32x4 v0 = ((const f32x4*)w)[2 * i];
    f32x4 v1 = ((const f32x4*)w)[2 * i + 1];
    float t[8];
    #pragma unroll
    for (int k = 0; k < 4; k++) {
      t[k]     = fminf(fmaxf(rintf(v0[k] * scale), -1.f), 1.f);
      t[4 + k] = fminf(fmaxf(rintf(v1[k] * scale), -1.f), 1.f);
    }
    u32x2 o;
    o[0] = pack4(t[0], t[1], t[2], t[3]);
    o[1] = pack4(t[4], t[5], t[6], t[7]);
    ((u32x2*)tern)[i] = o;
  }
}

// ---------------- RMSNorm + per-token int8 absmax quant (H=2048) ----------------
__global__ __launch_bounds__(256) void actq1_kernel(const float* __restrict__ x,
                                                    const float* __restrict__ g,
                                                    signed char* __restrict__ q,
                                                    float* __restrict__ a) {
  int t = blockIdx.x, tid = threadIdx.x;
  int lane = tid & 63, wv = tid >> 6;
  __shared__ float redS[4], redM[4];

  const f32x4* xr = (const f32x4*)(x + (size_t)t * 2048);
  f32x4 v0 = xr[tid * 2], v1 = xr[tid * 2 + 1];
  float ssq = 0.f;
  #pragma unroll
  for (int k = 0; k < 4; k++) ssq += v0[k] * v0[k] + v1[k] * v1[k];
  float ws_ = wave_sum(ssq);
  if (lane == 0) redS[wv] = ws_;
  __syncthreads();
  float tot = redS[0] + redS[1] + redS[2] + redS[3];
  float r = rsqrtf(tot / 2048.f + 1e-8f);

  f32x4 g0 = ((const f32x4*)g)[tid * 2], g1 = ((const f32x4*)g)[tid * 2 + 1];
  float h[8], amax = 0.f;
  #pragma unroll
  for (int k = 0; k < 4; k++) {
    h[k]     = v0[k] * r * g0[k];
    h[4 + k] = v1[k] * r * g1[k];
    amax = fmaxf(amax, fmaxf(fabsf(h[k]), fabsf(h[4 + k])));
  }
  float wm = wave_max(amax);
  if (lane == 0) redM[wv] = wm;
  __syncthreads();
  float am = fmaxf(fmaxf(fmaxf(redM[0], redM[1]), fmaxf(redM[2], redM[3])), 1e-5f);
  float scale = 127.f / am;

  float qv[8];
  #pragma unroll
  for (int k = 0; k < 8; k++) qv[k] = fminf(fmaxf(rintf(h[k] * scale), -128.f), 127.f);
  u32x2 o;
  o[0] = pack4(qv[0], qv[1], qv[2], qv[3]);
  o[1] = pack4(qv[4], qv[5], qv[6], qv[7]);
  ((u32x2*)(q + (size_t)t * 2048))[tid] = o;
  if (tid == 0) a[t] = am / 127.f;
}

// ---------------- SiLU(gate)*up + RMSNorm + quant (I=8192); y fp16 [T,16384] ----------------
__global__ __launch_bounds__(256) void silu_rms_q_kernel(const unsigned short* __restrict__ y,
                                                         const float* __restrict__ g,
                                                         signed char* __restrict__ q2,
                                                         float* __restrict__ a2) {
  int t = blockIdx.x, tid = threadIdx.x;
  int lane = tid & 63, wv = tid >> 6;
  __shared__ float redS[4], redM[4];
  const u32x4* gate = (const u32x4*)(y + (size_t)t * 16384);
  const u32x4* up   = (const u32x4*)(y + (size_t)t * 16384 + 8192);

  float v[32];
  float ssq = 0.f;
  #pragma unroll
  for (int b = 0; b < 4; b++) {
    u32x4 gr = gate[b * 256 + tid];
    u32x4 ur = up[b * 256 + tid];
    #pragma unroll
    for (int k = 0; k < 4; k++) {
      float g0 = __half2float(__ushort_as_half((unsigned short)(gr[k] & 0xFFFFu)));
      float g1 = __half2float(__ushort_as_half((unsigned short)(gr[k] >> 16)));
      float u0 = __half2float(__ushort_as_half((unsigned short)(ur[k] & 0xFFFFu)));
      float u1 = __half2float(__ushort_as_half((unsigned short)(ur[k] >> 16)));
      float v0 = g0 / (1.f + expf(-g0)) * u0;
      float v1 = g1 / (1.f + expf(-g1)) * u1;
      v[b * 8 + 2 * k] = v0;
      v[b * 8 + 2 * k + 1] = v1;
      ssq += v0 * v0 + v1 * v1;
    }
  }
  float ws_ = wave_sum(ssq);
  if (lane == 0) redS[wv] = ws_;
  __syncthreads();
  float tot = redS[0] + redS[1] + redS[2] + redS[3];
  float r = rsqrtf(tot / 8192.f + 1e-8f);

  float amax = 0.f;
  #pragma unroll
  for (int b = 0; b < 4; b++) {
    f32x4 ga = ((const f32x4*)g)[b * 512 + tid * 2];
    f32x4 gb = ((const f32x4*)g)[b * 512 + tid * 2 + 1];
    #pragma unroll
    for (int k = 0; k < 4; k++) {
      float h0 = v[b * 8 + k]     * r * ga[k];
      float h1 = v[b * 8 + 4 + k] * r * gb[k];
      v[b * 8 + k] = h0;
      v[b * 8 + 4 + k] = h1;
      amax = fmaxf(amax, fmaxf(fabsf(h0), fabsf(h1)));
    }
  }
  float wm = wave_max(amax);
  if (lane == 0) redM[wv] = wm;
  __syncthreads();
  float am = fmaxf(fmaxf(fmaxf(redM[0], redM[1]), fmaxf(redM[2], redM[3])), 1e-5f);
  float scale = 127.f / am;

  #pragma unroll
  for (int b = 0; b < 4; b++) {
    float qv[8];
    #pragma unroll
    for (int k = 0; k < 8; k++)
      qv[k] = fminf(fmaxf(rintf(v[b * 8 + k] * scale), -128.f), 127.f);
    u32x2 o;
    o[0] = pack4(qv[0], qv[1], qv[2], qv[3]);
    o[1] = pack4(qv[4], qv[5], qv[6], qv[7]);
    ((u32x2*)(q2 + (size_t)t * 8192))[b * 256 + tid] = o;
  }
  if (tid == 0) a2[t] = am / 127.f;
}

// ---------------- int8 MFMA GEMM 128x128 (kept for GEMM2): C = A * B^T ----------------
// OUT_MODE: 0 = fp16 (ushort), 1 = fp32 (float)
template <int OUT_MODE>
__global__ __launch_bounds__(256) void gemm_i8_kernel(const signed char* __restrict__ A,
                                                      const signed char* __restrict__ B,
                                                      void* __restrict__ Cv,
                                                      int M, int N, int K,
                                                      const float* __restrict__ rowscale,
                                                      const double* __restrict__ wsum, double inv_n) {
  __shared__ signed char As[8192];  // 128 rows x 64 cols (i8)
  __shared__ signed char Bs[8192];
  const int tid = threadIdx.x;
  const int lane = tid & 63;
  const int wv = tid >> 6;
  const int wm = wv >> 1, wn = wv & 1;
  const int m0 = blockIdx.y * 128;
  const int n0 = blockIdx.x * 128;

  const int rr = tid >> 2;            // staging row within 64-row half
  const int cc = (tid & 3) * 16;      // staging col (bytes)
  const signed char* Ag0 = A + (size_t)(m0 + rr) * K + cc;
  const signed char* Ag1 = A + (size_t)(m0 + 64 + rr) * K + cc;
  const signed char* Bg0 = B + (size_t)(n0 + rr) * K + cc;
  const signed char* Bg1 = B + (size_t)(n0 + 64 + rr) * K + cc;
  signed char* lA0 = &As[tid * 16];
  signed char* lA1 = &As[4096 + tid * 16];
  signed char* lB0 = &Bs[tid * 16];
  signed char* lB1 = &Bs[4096 + tid * 16];

  i32x4 acc[4][4] = {};

  const int fr = (lane & 15);
  const int kof = (lane >> 4) * 16;   // byte offset along K within a row

  for (int k0 = 0; k0 < K; k0 += 64) {
    gload16(Ag0 + k0, lA0);
    gload16(Ag1 + k0, lA1);
    gload16(Bg0 + k0, lB0);
    gload16(Bg1 + k0, lB1);
    __syncthreads();
    i32x4 af[4], bfr[4];
    #pragma unroll
    for (int i = 0; i < 4; i++)
      af[i] = *(const i32x4*)&As[(wm * 64 + i * 16 + fr) * 64 + kof];
    #pragma unroll
    for (int j = 0; j < 4; j++)
      bfr[j] = *(const i32x4*)&Bs[(wn * 64 + j * 16 + fr) * 64 + kof];
    #pragma unroll
    for (int i = 0; i < 4; i++)
      #pragma unroll
      for (int j = 0; j < 4; j++)
        acc[i][j] = __builtin_amdgcn_mfma_i32_16x16x64_i8(af[i], bfr[j], acc[i][j], 0, 0, 0);
    __syncthreads();
  }

  float sw = (float)fmax(*wsum * inv_n, 1e-5);
  const int q = lane >> 4;
  const int cbase = n0 + wn * 64 + (lane & 15);
  #pragma unroll
  for (int i = 0; i < 4; i++) {
    int rowb = m0 + wm * 64 + i * 16 + q * 4;
    #pragma unroll
    for (int r = 0; r < 4; r++) {
      float sc = rowscale[rowb + r] * sw;
      size_t off = (size_t)(rowb + r) * N + cbase;
      #pragma unroll
      for (int j = 0; j < 4; j++) {
        float vv = (float)acc[i][j][r] * sc;
        if (OUT_MODE == 0) ((unsigned short*)Cv)[off + j * 16] = __half_as_ushort(__float2half(vv));
        else               ((float*)Cv)[off + j * 16] = vv;
      }
    }
  }
}

// ================= 256x256 8-phase int8 MFMA GEMM (T1+T2+T3+T4+T5), fp16 out =================
// BM=BN=256, BK=128 i8, 512 threads (8 waves, 2x4), LDS 2 x (A 32K + B 32K) = 128 KiB.
// T2 involution (rule #21, BOTH sides identical):
//   write: LDS[r, chunk c] holds global chunk c ^ (r&7)   (pre-swizzled per-lane global column)
//   read : global chunk gc=(ks<<2)|qq lives at LDS chunk gc ^ (r&7)
//   *** round-1 bug: read XOR'd only qq (2 bits), excluding the ks bit -> half the rows
//       consumed the wrong K-half. Fixed: XOR all 3 chunk bits, computed per-ks in PHASE. ***
// T3/T4: 4 phases per K-tile, raw s_barrier (no vmcnt(0) drain), 2 gloads/phase staging t+1,
//   vmcnt(2) before each trailing barrier; staging order (B01|B23|A0A2|A1A3) matched to
//   consumption (P1 reads B+A{0,2}, P2 reads A{1,3}) so pending loads are never needed.
// T5: setprio(1) around each 16-MFMA cluster.

#define RD16(P, off) (*(const i32x4*)((P) + (off)))
#define MFMA_I8(a, b, c) __builtin_amdgcn_mfma_i32_16x16x64_i8((a), (b), (c), 0, 0, 0)
#define VM2 asm volatile("s_waitcnt vmcnt(2)" ::: "memory");
#define VM0 asm volatile("s_waitcnt vmcnt(0)" ::: "memory");
#define VMNONE

#define PHASE(ks, h, DOB, STAGE, WAITV) { \
  const int colb_ = ((((ks) << 6) | sq) ^ sfx);  /* ((ks<<2|qq)^ (fr&7)) * 16 */ \
  const int ab_ = arow0 + (h) * 8192 + colb_; \
  i32x4 fa0 = RD16(Ac, ab_); \
  i32x4 fa1 = RD16(Ac, ab_ + 2048); \
  i32x4 fa2 = RD16(Ac, ab_ + 4096); \
  i32x4 fa3 = RD16(Ac, ab_ + 6144); \
  if (DOB) { \
    const int bb_ = brow0 + colb_; \
    fb0 = RD16(Bc, bb_); \
    fb1 = RD16(Bc, bb_ + 2048); \
    fb2 = RD16(Bc, bb_ + 4096); \
    fb3 = RD16(Bc, bb_ + 6144); \
  } \
  STAGE; \
  __builtin_amdgcn_s_barrier(); \
  asm volatile("s_waitcnt lgkmcnt(0)" ::: "memory"); \
  __builtin_amdgcn_s_setprio(1); \
  acc[(h) * 4 + 0][0] = MFMA_I8(fa0, fb0, acc[(h) * 4 + 0][0]); \
  acc[(h) * 4 + 0][1] = MFMA_I8(fa0, fb1, acc[(h) * 4 + 0][1]); \
  acc[(h) * 4 + 0][2] = MFMA_I8(fa0, fb2, acc[(h) * 4 + 0][2]); \
  acc[(h) * 4 + 0][3] = MFMA_I8(fa0, fb3, acc[(h) * 4 + 0][3]); \
  acc[(h) * 4 + 1][0] = MFMA_I8(fa1, fb0, acc[(h) * 4 + 1][0]); \
  acc[(h) * 4 + 1][1] = MFMA_I8(fa1, fb1, acc[(h) * 4 + 1][1]); \
  acc[(h) * 4 + 1][2] = MFMA_I8(fa1, fb2, acc[(h) * 4 + 1][2]); \
  acc[(h) * 4 + 1][3] = MFMA_I8(fa1, fb3, acc[(h) * 4 + 1][3]); \
  acc[(h) * 4 + 2][0] = MFMA_I8(fa2, fb0, acc[(h) * 4 + 2][0]); \
  acc[(h) * 4 + 2][1] = MFMA_I8(fa2, fb1, acc[(h) * 4 + 2][1]); \
  acc[(h) * 4 + 2][2] = MFMA_I8(fa2, fb2, acc[(h) * 4 + 2][2]); \
  acc[(h) * 4 + 2][3] = MFMA_I8(fa2, fb3, acc[(h) * 4 + 2][3]); \
  acc[(h) * 4 + 3][0] = MFMA_I8(fa3, fb0, acc[(h) * 4 + 3][0]); \
  acc[(h) * 4 + 3][1] = MFMA_I8(fa3, fb1, acc[(h) * 4 + 3][1]); \
  acc[(h) * 4 + 3][2] = MFMA_I8(fa3, fb2, acc[(h) * 4 + 3][2]); \
  acc[(h) * 4 + 3][3] = MFMA_I8(fa3, fb3, acc[(h) * 4 + 3][3]); \
  __builtin_amdgcn_s_setprio(0); \
  WAITV \
  __builtin_amdgcn_s_barrier(); }

__global__ __launch_bounds__(512, 2) void gemm256_i8_kernel(
    const signed char* __restrict__ A, const signed char* __restrict__ B,
    unsigned short* __restrict__ C, int M, int N, int K,
    const float* __restrict__ rowscale, const double* __restrict__ wsum, double inv_n) {
  __shared__ __align__(16) signed char lds[131072];
  const int tid = threadIdx.x;
  const int lane = tid & 63;
  const int wid = tid >> 6;
  const int wr = wid >> 2;   // 0..1 -> 128 output rows each
  const int wc = wid & 3;    // 0..3 -> 64 output cols each

  // T1: XCD-aware block swizzle (gridDim.x % 8 == 0)
  const int nbn = N >> 8;
  const int b = blockIdx.x;
  const int cpx = gridDim.x >> 3;
  const int sb = (b & 7) * cpx + (b >> 3);
  const int m0 = (sb / nbn) << 8;
  const int n0 = (sb % nbn) << 8;

  // fragment-read addressing (T2 swizzle on read side; ks bit folded in per-phase)
  const int fr = lane & 15;            // row within 16-row frag
  const int sq = (lane >> 4) << 4;     // qq*16 (16B K-chunk within 64B K-slice)
  const int sfx = (fr & 7) << 4;       // swizzle XOR term
  const int arow0 = (wr * 128 + fr) * 128;  // + h*8192 + m*2048 + colb
  const int brow0 = (wc * 64 + fr) * 128;   // + n*2048 + colb

  // staging source (T2 swizzle pre-applied to global column; LDS dest stays linear)
  const int rr = tid >> 3;                         // row within 64-row group
  const int co = (((tid & 7) ^ (rr & 7)) << 4);    // swizzled source column
  const signed char* gA = A + (size_t)(m0 + rr) * K + co;
  const signed char* gB = B + (size_t)(n0 + rr) * K + co;
  const size_t g64 = (size_t)64 * K;

  i32x4 acc[8][4] = {};
  i32x4 fb0, fb1, fb2, fb3;
  const int NT = K >> 7;

  // prologue: stage tile 0 into buf0; issue order B0 B1 B2 B3 A0 A2 | A1 A3
  // (loop invariant: at tile start only the 2 newest loads {A1,A3} may be pending)
  {
    signed char* Ad = lds + tid * 16;
    signed char* Bd = Ad + 32768;
    gload16(gB,           Bd);
    gload16(gB + g64,     Bd + 8192);
    gload16(gB + 2 * g64, Bd + 16384);
    gload16(gB + 3 * g64, Bd + 24576);
    gload16(gA,           Ad);
    gload16(gA + 2 * g64, Ad + 16384);
    gload16(gA + g64,     Ad + 8192);
    gload16(gA + 3 * g64, Ad + 24576);
    VM2
    __builtin_amdgcn_s_barrier();
  }

  for (int t = 0; t < NT - 1; ++t) {
    const signed char* Ac = lds + ((t & 1) << 16);
    const signed char* Bc = Ac + 32768;
    signed char* Ad = lds + (((t & 1) ^ 1) << 16) + tid * 16;
    signed char* Bd = Ad + 32768;
    const signed char* gAt = gA + (size_t)(t + 1) * 128;
    const signed char* gBt = gB + (size_t)(t + 1) * 128;

    // P1 (ks0,h0): reads A grp{0,2} (staged 2 phases back) + all B; stages B0,B1 of t+1
    PHASE(0, 0, 1, gload16(gBt, Bd); gload16(gBt + g64, Bd + 8192), VM2)
    // P2 (ks0,h1): reads A grp{1,3} (drained by P1's vmcnt); stages B2,B3
    PHASE(0, 1, 0, gload16(gBt + 2 * g64, Bd + 16384); gload16(gBt + 3 * g64, Bd + 24576), VM2)
    // P3 (ks1,h0): stages A0,A2
    PHASE(1, 0, 1, gload16(gAt, Ad); gload16(gAt + 2 * g64, Ad + 16384), VM2)
    // P4 (ks1,h1): stages A1,A3 (the 2 allowed in flight across the tile boundary)
    PHASE(1, 1, 0, gload16(gAt + g64, Ad + 8192); gload16(gAt + 3 * g64, Ad + 24576), VM2)
  }

  // tail tile: no staging; drain the pending {A1,A3} before P2 needs them
  {
    const signed char* Ac = lds + (((NT - 1) & 1) << 16);
    const signed char* Bc = Ac + 32768;
    PHASE(0, 0, 1, , VM0)
    PHASE(0, 1, 0, , VMNONE)
    PHASE(1, 0, 1, , VMNONE)
    PHASE(1, 1, 0, , VMNONE)
  }

  // epilogue: C/D map col = lane&15, row = (lane>>4)*4 + reg (verified layout)
  float sw = (float)fmax(*wsum * inv_n, 1e-5);
  const int qo = lane >> 4;
  const int cb = n0 + wc * 64 + fr;
  #pragma unroll
  for (int ai = 0; ai < 8; ai++) {
    const int rowb = m0 + wr * 128 + ai * 16 + qo * 4;
    #pragma unroll
    for (int r = 0; r < 4; r++) {
      float sc = rowscale[rowb + r] * sw;
      size_t off = (size_t)(rowb + r) * N + cb;
      #pragma unroll
      for (int n = 0; n < 4; n++)
        C[off + n * 16] = __half_as_ushort(__float2half((float)acc[ai][n][r] * sc));
    }
  }
}

extern "C" void kernel_launch(void* const* d_in, const int* in_sizes, int n_in,
                              void* d_out, int out_size, void* d_ws, size_t ws_size,
                              hipStream_t stream) {
  const float* x      = (const float*)d_in[0];
  const float* w_gate = (const float*)d_in[1];
  const float* g_gate = (const float*)d_in[2];
  const float* w_down = (const float*)d_in[3];
  const float* g_down = (const float*)d_in[4];
  float* out = (float*)d_out;

  char* ws = (char*)d_ws;
  double* sums = (double*)ws;                                    // 2 doubles
  float* a1 = (float*)(ws + 4096);                               // 4096 f32
  float* a2 = (float*)(ws + 20480);                              // 4096 f32
  const size_t MB = 1024 * 1024;
  signed char* tern_g = (signed char*)(ws + 65536);              // 16384x2048 i8 = 32 MiB
  signed char* q2     = tern_g;                                  // alias: tern_g dead after GEMM1 (32 MiB)
  signed char* tern_d = (signed char*)(ws + 65536 + 32 * MB);    // 2048x8192 i8 = 16 MiB
  signed char* q1     = (signed char*)(ws + 65536 + 48 * MB);    // 4096x2048 i8 = 8 MiB
  unsigned short* yh  = (unsigned short*)(ws + 65536 + 56 * MB); // 4096x16384 fp16 = 128 MiB

  hipMemsetAsync(sums, 0, 16, stream);
  absum_kernel<<<2048, 256, 0, stream>>>(w_gate, 33554432LL / 4, sums + 0);
  absum_kernel<<<1024, 256, 0, stream>>>(w_down, 16777216LL / 4, sums + 1);
  quantw_kernel<<<4096, 256, 0, stream>>>(w_gate, tern_g, 33554432LL / 8, sums + 0, 1.0 / 33554432.0);
  quantw_kernel<<<2048, 256, 0, stream>>>(w_down, tern_d, 16777216LL / 8, sums + 1, 1.0 / 16777216.0);
  actq1_kernel<<<4096, 256, 0, stream>>>(x, g_gate, q1, a1);
  // GEMM1: M=4096, N=16384, K=2048 -> 1024 blocks of 256x256
  gemm256_i8_kernel<<<1024, 512, 0, stream>>>(q1, tern_g, yh, 4096, 16384, 2048,
                                              a1, sums + 0, 1.0 / 33554432.0);
  silu_rms_q_kernel<<<4096, 256, 0, stream>>>(yh, g_down, q2, a2);
  // GEMM2: N=2048 -> only 128 blocks at 256 tiles (half the CUs idle) -> keep 128x128 kernel
  gemm_i8_kernel<1><<<dim3(16, 32), 256, 0, stream>>>(q2, tern_d, out, 4096, 2048, 8192,
                                                      a2, sums + 1, 1.0 / 16777216.0);
}

// Round 3
// 595.001 us; speedup vs baseline: 1.1146x; 1.0379x over previous
//
#include <hip/hip_runtime.h>
#include <hip/hip_bf16.h>
#include <hip/hip_fp16.h>

#define DEVINL __device__ __forceinline__

typedef float f32x4 __attribute__((ext_vector_type(4)));
typedef int i32x4 __attribute__((ext_vector_type(4)));
typedef unsigned int u32x4 __attribute__((ext_vector_type(4)));
typedef unsigned int u32x2 __attribute__((ext_vector_type(2)));

typedef __attribute__((address_space(1))) void void_g;
typedef __attribute__((address_space(3))) void void_l;

DEVINL void gload16(const void* g, void* l) {
  // async global->LDS, 16B/lane; LDS dst must be wave-uniform base + lane*16
  __builtin_amdgcn_global_load_lds((void_g*)g, (void_l*)l, 16, 0, 0);
}

DEVINL float wave_sum(float v) {
  #pragma unroll
  for (int o = 32; o > 0; o >>= 1) v += __shfl_down(v, o, 64);
  return v;
}
DEVINL float wave_max(float v) {
  #pragma unroll
  for (int o = 32; o > 0; o >>= 1) v = fmaxf(v, __shfl_down(v, o, 64));
  return v;
}

// pack 4 already-rounded-and-clamped floats into 4 signed bytes
DEVINL unsigned int pack4(float a, float b, float c, float d) {
  return ((unsigned int)(unsigned char)(signed char)(int)a)
       | (((unsigned int)(unsigned char)(signed char)(int)b) << 8)
       | (((unsigned int)(unsigned char)(signed char)(int)c) << 16)
       | (((unsigned int)(unsigned char)(signed char)(int)d) << 24);
}

// ---------------- sum(|w|) over fp32 tensor -> double ----------------
__global__ __launch_bounds__(256) void absum_kernel(const float* __restrict__ w,
                                                    long long nchunk, double* __restrict__ out) {
  long long stride = (long long)gridDim.x * 256;
  long long i = (long long)blockIdx.x * 256 + threadIdx.x;
  float s = 0.f;
  for (; i < nchunk; i += stride) {
    f32x4 v = ((const f32x4*)w)[i];
    s += fabsf(v[0]) + fabsf(v[1]) + fabsf(v[2]) + fabsf(v[3]);
  }
  s = wave_sum(s);
  __shared__ float red[4];
  int lane = threadIdx.x & 63, wv = threadIdx.x >> 6;
  if (lane == 0) red[wv] = s;
  __syncthreads();
  if (threadIdx.x == 0) atomicAdd(out, (double)(red[0] + red[1] + red[2] + red[3]));
}

// ---------------- ternary weight quant -> int8 {-1,0,1} ----------------
__global__ __launch_bounds__(256) void quantw_kernel(const float* __restrict__ w,
                                                     signed char* __restrict__ tern,
                                                     long long nchunk,  // groups of 8 floats
                                                     const double* __restrict__ sum, double inv_n) {
  float scale = (float)(1.0 / fmax(*sum * inv_n, 1e-5));
  long long stride = (long long)gridDim.x * 256;
  long long i = (long long)blockIdx.x * 256 + threadIdx.x;
  for (; i < nchunk; i += stride) {
    f32x4 v0 = ((const f32x4*)w)[2 * i];
    f32x4 v1 = ((const f32x4*)w)[2 * i + 1];
    float t[8];
    #pragma unroll
    for (int k = 0; k < 4; k++) {
      t[k]     = fminf(fmaxf(rintf(v0[k] * scale), -1.f), 1.f);
      t[4 + k] = fminf(fmaxf(rintf(v1[k] * scale), -1.f), 1.f);
    }
    u32x2 o;
    o[0] = pack4(t[0], t[1], t[2], t[3]);
    o[1] = pack4(t[4], t[5], t[6], t[7]);
    ((u32x2*)tern)[i] = o;
  }
}

// ---------------- RMSNorm + per-token int8 absmax quant (H=2048) ----------------
__global__ __launch_bounds__(256) void actq1_kernel(const float* __restrict__ x,
                                                    const float* __restrict__ g,
                                                    signed char* __restrict__ q,
                                                    float* __restrict__ a) {
  int t = blockIdx.x, tid = threadIdx.x;
  int lane = tid & 63, wv = tid >> 6;
  __shared__ float redS[4], redM[4];

  const f32x4* xr = (const f32x4*)(x + (size_t)t * 2048);
  f32x4 v0 = xr[tid * 2], v1 = xr[tid * 2 + 1];
  float ssq = 0.f;
  #pragma unroll
  for (int k = 0; k < 4; k++) ssq += v0[k] * v0[k] + v1[k] * v1[k];
  float ws_ = wave_sum(ssq);
  if (lane == 0) redS[wv] = ws_;
  __syncthreads();
  float tot = redS[0] + redS[1] + redS[2] + redS[3];
  float r = rsqrtf(tot / 2048.f + 1e-8f);

  f32x4 g0 = ((const f32x4*)g)[tid * 2], g1 = ((const f32x4*)g)[tid * 2 + 1];
  float h[8], amax = 0.f;
  #pragma unroll
  for (int k = 0; k < 4; k++) {
    h[k]     = v0[k] * r * g0[k];
    h[4 + k] = v1[k] * r * g1[k];
    amax = fmaxf(amax, fmaxf(fabsf(h[k]), fabsf(h[4 + k])));
  }
  float wm = wave_max(amax);
  if (lane == 0) redM[wv] = wm;
  __syncthreads();
  float am = fmaxf(fmaxf(fmaxf(redM[0], redM[1]), fmaxf(redM[2], redM[3])), 1e-5f);
  float scale = 127.f / am;

  float qv[8];
  #pragma unroll
  for (int k = 0; k < 8; k++) qv[k] = fminf(fmaxf(rintf(h[k] * scale), -128.f), 127.f);
  u32x2 o;
  o[0] = pack4(qv[0], qv[1], qv[2], qv[3]);
  o[1] = pack4(qv[4], qv[5], qv[6], qv[7]);
  ((u32x2*)(q + (size_t)t * 2048))[tid] = o;
  if (tid == 0) a[t] = am / 127.f;
}

// ---------------- SiLU(gate)*up + RMSNorm + quant (I=8192); y fp16 [T,16384] ----------------
__global__ __launch_bounds__(256) void silu_rms_q_kernel(const unsigned short* __restrict__ y,
                                                         const float* __restrict__ g,
                                                         signed char* __restrict__ q2,
                                                         float* __restrict__ a2) {
  int t = blockIdx.x, tid = threadIdx.x;
  int lane = tid & 63, wv = tid >> 6;
  __shared__ float redS[4], redM[4];
  const u32x4* gate = (const u32x4*)(y + (size_t)t * 16384);
  const u32x4* up   = (const u32x4*)(y + (size_t)t * 16384 + 8192);

  float v[32];
  float ssq = 0.f;
  #pragma unroll
  for (int b = 0; b < 4; b++) {
    u32x4 gr = gate[b * 256 + tid];
    u32x4 ur = up[b * 256 + tid];
    #pragma unroll
    for (int k = 0; k < 4; k++) {
      float g0 = __half2float(__ushort_as_half((unsigned short)(gr[k] & 0xFFFFu)));
      float g1 = __half2float(__ushort_as_half((unsigned short)(gr[k] >> 16)));
      float u0 = __half2float(__ushort_as_half((unsigned short)(ur[k] & 0xFFFFu)));
      float u1 = __half2float(__ushort_as_half((unsigned short)(ur[k] >> 16)));
      float v0 = g0 / (1.f + expf(-g0)) * u0;
      float v1 = g1 / (1.f + expf(-g1)) * u1;
      v[b * 8 + 2 * k] = v0;
      v[b * 8 + 2 * k + 1] = v1;
      ssq += v0 * v0 + v1 * v1;
    }
  }
  float ws_ = wave_sum(ssq);
  if (lane == 0) redS[wv] = ws_;
  __syncthreads();
  float tot = redS[0] + redS[1] + redS[2] + redS[3];
  float r = rsqrtf(tot / 8192.f + 1e-8f);

  float amax = 0.f;
  #pragma unroll
  for (int b = 0; b < 4; b++) {
    f32x4 ga = ((const f32x4*)g)[b * 512 + tid * 2];
    f32x4 gb = ((const f32x4*)g)[b * 512 + tid * 2 + 1];
    #pragma unroll
    for (int k = 0; k < 4; k++) {
      float h0 = v[b * 8 + k]     * r * ga[k];
      float h1 = v[b * 8 + 4 + k] * r * gb[k];
      v[b * 8 + k] = h0;
      v[b * 8 + 4 + k] = h1;
      amax = fmaxf(amax, fmaxf(fabsf(h0), fabsf(h1)));
    }
  }
  float wm = wave_max(amax);
  if (lane == 0) redM[wv] = wm;
  __syncthreads();
  float am = fmaxf(fmaxf(fmaxf(redM[0], redM[1]), fmaxf(redM[2], redM[3])), 1e-5f);
  float scale = 127.f / am;

  #pragma unroll
  for (int b = 0; b < 4; b++) {
    float qv[8];
    #pragma unroll
    for (int k = 0; k < 8; k++)
      qv[k] = fminf(fmaxf(rintf(v[b * 8 + k] * scale), -128.f), 127.f);
    u32x2 o;
    o[0] = pack4(qv[0], qv[1], qv[2], qv[3]);
    o[1] = pack4(qv[4], qv[5], qv[6], qv[7]);
    ((u32x2*)(q2 + (size_t)t * 8192))[b * 256 + tid] = o;
  }
  if (tid == 0) a2[t] = am / 127.f;
}

// ================= 256x256 int8 MFMA GEMM, 1-barrier pipelined tile =================
// BM=BN=256, BK=128 i8, 512 threads (8 waves, 2x4), LDS 2 x (A 32K + B 32K) = 128 KiB.
// T2 involution (verified r2): LDS[g][rr][c] = global[rr][c ^ (rr&7)] (chunks of 16B);
//   read chunk for (ks,qq) at LDS chunk ((ks<<2)|qq) ^ (fr&7). Bank-conflict-free (PMC=0).
// Schedule (r3): ONE s_barrier + ONE vmcnt(0) per K-tile. All 4 MFMA clusters of a tile
//   read the same stable LDS buffer -> no intra-tile barriers. ds_reads for cluster k+1
//   are issued before cluster k's MFMAs (compiler inserts the lgkmcnt for the reg deps),
//   so LDS drain hides under MFMA. Staging for t+1 spread 3/3/2 across the tile; youngest
//   loads get >=2 clusters (~1300 cyc > 900 cyc HBM) of cover before the boundary vmcnt(0),
//   which guarantees ALL 8 groups of t+1 at the boundary barrier (no mid-tile visibility
//   constraint). r2's per-phase vmcnt(2) at P2/P3 waited on 1-phase-old loads needed 3
//   phases later - pure exposed latency, removed.
// T5: setprio(1) around each 16-MFMA cluster. T1: bijective XCD swizzle (grid % 8 == 0).

#define RD16(P, off) (*(const i32x4*)((P) + (off)))
#define MFMA_I8(a, b, c) __builtin_amdgcn_mfma_i32_16x16x64_i8((a), (b), (c), 0, 0, 0)
#define VM0 asm volatile("s_waitcnt vmcnt(0)" ::: "memory");

#define CB(ks) ((((ks) << 6) | sq) ^ sfx)
#define RDA(d0_, d1_, d2_, d3_, h, ks) { const int o_ = arow0 + (h) * 8192 + CB(ks); \
  d0_ = RD16(Ac, o_); d1_ = RD16(Ac, o_ + 2048); d2_ = RD16(Ac, o_ + 4096); d3_ = RD16(Ac, o_ + 6144); }
#define RDB(d0_, d1_, d2_, d3_, ks) { const int o_ = brow0 + CB(ks); \
  d0_ = RD16(Bc, o_); d1_ = RD16(Bc, o_ + 2048); d2_ = RD16(Bc, o_ + 4096); d3_ = RD16(Bc, o_ + 6144); }

#define CL(h, A0_, A1_, A2_, A3_, B0_, B1_, B2_, B3_) \
  __builtin_amdgcn_s_setprio(1); \
  acc[(h)*4+0][0] = MFMA_I8(A0_, B0_, acc[(h)*4+0][0]); \
  acc[(h)*4+0][1] = MFMA_I8(A0_, B1_, acc[(h)*4+0][1]); \
  acc[(h)*4+0][2] = MFMA_I8(A0_, B2_, acc[(h)*4+0][2]); \
  acc[(h)*4+0][3] = MFMA_I8(A0_, B3_, acc[(h)*4+0][3]); \
  acc[(h)*4+1][0] = MFMA_I8(A1_, B0_, acc[(h)*4+1][0]); \
  acc[(h)*4+1][1] = MFMA_I8(A1_, B1_, acc[(h)*4+1][1]); \
  acc[(h)*4+1][2] = MFMA_I8(A1_, B2_, acc[(h)*4+1][2]); \
  acc[(h)*4+1][3] = MFMA_I8(A1_, B3_, acc[(h)*4+1][3]); \
  acc[(h)*4+2][0] = MFMA_I8(A2_, B0_, acc[(h)*4+2][0]); \
  acc[(h)*4+2][1] = MFMA_I8(A2_, B1_, acc[(h)*4+2][1]); \
  acc[(h)*4+2][2] = MFMA_I8(A2_, B2_, acc[(h)*4+2][2]); \
  acc[(h)*4+2][3] = MFMA_I8(A2_, B3_, acc[(h)*4+2][3]); \
  acc[(h)*4+3][0] = MFMA_I8(A3_, B0_, acc[(h)*4+3][0]); \
  acc[(h)*4+3][1] = MFMA_I8(A3_, B1_, acc[(h)*4+3][1]); \
  acc[(h)*4+3][2] = MFMA_I8(A3_, B2_, acc[(h)*4+3][2]); \
  acc[(h)*4+3][3] = MFMA_I8(A3_, B3_, acc[(h)*4+3][3]); \
  __builtin_amdgcn_s_setprio(0);

// S1/S2/S3 are staging statements (empty in the tail tile).
#define TILE_BODY(S1, S2, S3) { \
  i32x4 a0, a1, a2, a3, b0, b1, b2, b3, c0, c1, c2, c3, d0, d1, d2, d3; \
  RDA(a0, a1, a2, a3, 0, 0)            /* (h0,ks0) A  : groups {0,2} */ \
  RDB(b0, b1, b2, b3, 0)               /* ks0 B */ \
  S1 \
  RDA(c0, c1, c2, c3, 1, 0)            /* (h1,ks0) A : groups {1,3} */ \
  CL(0, a0, a1, a2, a3, b0, b1, b2, b3)              /* M1 */ \
  RDA(d0, d1, d2, d3, 0, 1)            /* (h0,ks1) A */ \
  RDB(a0, a1, a2, a3, 1)               /* ks1 B (a* dead after M1) */ \
  S2 \
  CL(1, c0, c1, c2, c3, b0, b1, b2, b3)              /* M2 */ \
  RDA(b0, b1, b2, b3, 1, 1)            /* (h1,ks1) A (b* dead after M2) */ \
  S3 \
  CL(0, d0, d1, d2, d3, a0, a1, a2, a3)              /* M3 */ \
  CL(1, b0, b1, b2, b3, a0, a1, a2, a3)              /* M4 */ \
}

// OUT_MODE: 0 = fp16 (ushort), 1 = fp32 (float)
template <int OUT_MODE>
__global__ __launch_bounds__(512, 2) void gemm256_i8_kernel(
    const signed char* __restrict__ A, const signed char* __restrict__ B,
    void* __restrict__ Cv, int M, int N, int K,
    const float* __restrict__ rowscale, const double* __restrict__ wsum, double inv_n) {
  __shared__ __align__(16) signed char lds[131072];
  const int tid = threadIdx.x;
  const int lane = tid & 63;
  const int wid = tid >> 6;
  const int wr = wid >> 2;   // 0..1 -> 128 output rows each
  const int wc = wid & 3;    // 0..3 -> 64 output cols each

  // T1: XCD-aware block swizzle (gridDim.x % 8 == 0)
  const int nbn = N >> 8;
  const int b = blockIdx.x;
  const int cpx = gridDim.x >> 3;
  const int sb = (b & 7) * cpx + (b >> 3);
  const int m0 = (sb / nbn) << 8;
  const int n0 = (sb % nbn) << 8;

  // fragment-read addressing (T2 swizzle on read side; ks bit folded into the XOR)
  const int fr = lane & 15;            // row within 16-row frag
  const int sq = (lane >> 4) << 4;     // qq*16 (16B K-chunk)
  const int sfx = (fr & 7) << 4;       // swizzle XOR term
  const int arow0 = (wr * 128 + fr) * 128;
  const int brow0 = (wc * 64 + fr) * 128;

  // staging source (T2 swizzle pre-applied to global column; LDS dest stays linear)
  const int rr = tid >> 3;                         // row within 64-row group
  const int co = (((tid & 7) ^ (rr & 7)) << 4);    // swizzled source column
  const signed char* gA = A + (size_t)(m0 + rr) * K + co;
  const signed char* gB = B + (size_t)(n0 + rr) * K + co;
  const size_t g64 = (size_t)64 * K;

  i32x4 acc[8][4] = {};
  const int NT = K >> 7;

  // prologue: stage all 8 groups of tile 0 into buf0
  {
    signed char* Ad = lds + tid * 16;
    signed char* Bd = Ad + 32768;
    gload16(gB,           Bd);
    gload16(gB + g64,     Bd + 8192);
    gload16(gB + 2 * g64, Bd + 16384);
    gload16(gB + 3 * g64, Bd + 24576);
    gload16(gA,           Ad);
    gload16(gA + g64,     Ad + 8192);
    gload16(gA + 2 * g64, Ad + 16384);
    gload16(gA + 3 * g64, Ad + 24576);
    VM0
    __builtin_amdgcn_s_barrier();
  }

  for (int t = 0; t < NT - 1; ++t) {
    const signed char* Ac = lds + ((t & 1) << 16);
    const signed char* Bc = Ac + 32768;
    signed char* Ad = lds + (((t & 1) ^ 1) << 16) + tid * 16;
    signed char* Bd = Ad + 32768;
    const signed char* gAt = gA + (size_t)(t + 1) * 128;
    const signed char* gBt = gB + (size_t)(t + 1) * 128;

    TILE_BODY(
      gload16(gBt, Bd); gload16(gBt + g64, Bd + 8192); gload16(gBt + 2 * g64, Bd + 16384); ,
      gload16(gBt + 3 * g64, Bd + 24576); gload16(gAt, Ad); gload16(gAt + 2 * g64, Ad + 16384); ,
      gload16(gAt + g64, Ad + 8192); gload16(gAt + 3 * g64, Ad + 24576); )

    VM0                              // youngest loads issued >=2 MFMA clusters ago
    __builtin_amdgcn_s_barrier();    // all 8 groups of tile t+1 now visible to all waves
  }

  // tail tile: no staging, no sync needed after (epilogue reads only registers)
  {
    const signed char* Ac = lds + (((NT - 1) & 1) << 16);
    const signed char* Bc = Ac + 32768;
    TILE_BODY(, , )
  }

  // epilogue: C/D map col = lane&15, row = (lane>>4)*4 + reg (verified layout)
  float sw = (float)fmax(*wsum * inv_n, 1e-5);
  const int qo = lane >> 4;
  const int cb = n0 + wc * 64 + fr;
  #pragma unroll
  for (int ai = 0; ai < 8; ai++) {
    const int rowb = m0 + wr * 128 + ai * 16 + qo * 4;
    #pragma unroll
    for (int r = 0; r < 4; r++) {
      float sc = rowscale[rowb + r] * sw;
      size_t off = (size_t)(rowb + r) * N + cb;
      #pragma unroll
      for (int n = 0; n < 4; n++) {
        float vv = (float)acc[ai][n][r] * sc;
        if (OUT_MODE == 0) ((unsigned short*)Cv)[off + n * 16] = __half_as_ushort(__float2half(vv));
        else               ((float*)Cv)[off + n * 16] = vv;
      }
    }
  }
}

extern "C" void kernel_launch(void* const* d_in, const int* in_sizes, int n_in,
                              void* d_out, int out_size, void* d_ws, size_t ws_size,
                              hipStream_t stream) {
  const float* x      = (const float*)d_in[0];
  const float* w_gate = (const float*)d_in[1];
  const float* g_gate = (const float*)d_in[2];
  const float* w_down = (const float*)d_in[3];
  const float* g_down = (const float*)d_in[4];
  float* out = (float*)d_out;

  char* ws = (char*)d_ws;
  double* sums = (double*)ws;                                    // 2 doubles
  float* a1 = (float*)(ws + 4096);                               // 4096 f32
  float* a2 = (float*)(ws + 20480);                              // 4096 f32
  const size_t MB = 1024 * 1024;
  signed char* tern_g = (signed char*)(ws + 65536);              // 16384x2048 i8 = 32 MiB
  signed char* q2     = tern_g;                                  // alias: tern_g dead after GEMM1 (32 MiB)
  signed char* tern_d = (signed char*)(ws + 65536 + 32 * MB);    // 2048x8192 i8 = 16 MiB
  signed char* q1     = (signed char*)(ws + 65536 + 48 * MB);    // 4096x2048 i8 = 8 MiB
  unsigned short* yh  = (unsigned short*)(ws + 65536 + 56 * MB); // 4096x16384 fp16 = 128 MiB

  hipMemsetAsync(sums, 0, 16, stream);
  absum_kernel<<<2048, 256, 0, stream>>>(w_gate, 33554432LL / 4, sums + 0);
  absum_kernel<<<1024, 256, 0, stream>>>(w_down, 16777216LL / 4, sums + 1);
  quantw_kernel<<<4096, 256, 0, stream>>>(w_gate, tern_g, 33554432LL / 8, sums + 0, 1.0 / 33554432.0);
  quantw_kernel<<<2048, 256, 0, stream>>>(w_down, tern_d, 16777216LL / 8, sums + 1, 1.0 / 16777216.0);
  actq1_kernel<<<4096, 256, 0, stream>>>(x, g_gate, q1, a1);
  // GEMM1: M=4096, N=16384, K=2048 -> 1024 blocks of 256x256
  gemm256_i8_kernel<0><<<1024, 512, 0, stream>>>(q1, tern_g, yh, 4096, 16384, 2048,
                                                 a1, sums + 0, 1.0 / 33554432.0);
  silu_rms_q_kernel<<<4096, 256, 0, stream>>>(yh, g_down, q2, a2);
  // GEMM2: M=4096, N=2048, K=8192 -> 128 blocks of 256x256 (half the CUs, but 64-deep K
  // pipeline; replaces the syncthreads-bound 128^2 kernel)
  gemm256_i8_kernel<1><<<128, 512, 0, stream>>>(q2, tern_d, out, 4096, 2048, 8192,
                                                a2, sums + 1, 1.0 / 16777216.0);
}

// Round 5
// 591.783 us; speedup vs baseline: 1.1206x; 1.0054x over previous
//
#include <hip/hip_runtime.h>
#include <hip/hip_bf16.h>
#include <hip/hip_fp16.h>

#define DEVINL __device__ __forceinline__

typedef float f32x4 __attribute__((ext_vector_type(4)));
typedef int i32x4 __attribute__((ext_vector_type(4)));
typedef unsigned int u32x4 __attribute__((ext_vector_type(4)));
typedef unsigned int u32x2 __attribute__((ext_vector_type(2)));

typedef __attribute__((address_space(1))) void void_g;
typedef __attribute__((address_space(3))) void void_l;

DEVINL void gload16(const void* g, void* l) {
  // async global->LDS, 16B/lane; LDS dst must be wave-uniform base + lane*16
  __builtin_amdgcn_global_load_lds((void_g*)g, (void_l*)l, 16, 0, 0);
}

DEVINL float wave_sum(float v) {
  #pragma unroll
  for (int o = 32; o > 0; o >>= 1) v += __shfl_down(v, o, 64);
  return v;
}
DEVINL float wave_max(float v) {
  #pragma unroll
  for (int o = 32; o > 0; o >>= 1) v = fmaxf(v, __shfl_down(v, o, 64));
  return v;
}

// pack 4 already-rounded-and-clamped floats into 4 signed bytes
DEVINL unsigned int pack4(float a, float b, float c, float d) {
  return ((unsigned int)(unsigned char)(signed char)(int)a)
       | (((unsigned int)(unsigned char)(signed char)(int)b) << 8)
       | (((unsigned int)(unsigned char)(signed char)(int)c) << 16)
       | (((unsigned int)(unsigned char)(signed char)(int)d) << 24);
}

// ---------------- sum(|w|) over fp32 tensor -> double ----------------
__global__ __launch_bounds__(256) void absum_kernel(const float* __restrict__ w,
                                                    long long nchunk, double* __restrict__ out) {
  long long stride = (long long)gridDim.x * 256;
  long long i = (long long)blockIdx.x * 256 + threadIdx.x;
  float s = 0.f;
  for (; i < nchunk; i += stride) {
    f32x4 v = ((const f32x4*)w)[i];
    s += fabsf(v[0]) + fabsf(v[1]) + fabsf(v[2]) + fabsf(v[3]);
  }
  s = wave_sum(s);
  __shared__ float red[4];
  int lane = threadIdx.x & 63, wv = threadIdx.x >> 6;
  if (lane == 0) red[wv] = s;
  __syncthreads();
  if (threadIdx.x == 0) atomicAdd(out, (double)(red[0] + red[1] + red[2] + red[3]));
}

// ---------------- ternary weight quant -> int8 {-1,0,1} ----------------
__global__ __launch_bounds__(256) void quantw_kernel(const float* __restrict__ w,
                                                     signed char* __restrict__ tern,
                                                     long long nchunk,  // groups of 8 floats
                                                     const double* __restrict__ sum, double inv_n) {
  float scale = (float)(1.0 / fmax(*sum * inv_n, 1e-5));
  long long stride = (long long)gridDim.x * 256;
  long long i = (long long)blockIdx.x * 256 + threadIdx.x;
  for (; i < nchunk; i += stride) {
    f32x4 v0 = ((const f32x4*)w)[2 * i];
    f32x4 v1 = ((const f32x4*)w)[2 * i + 1];
    float t[8];
    #pragma unroll
    for (int k = 0; k < 4; k++) {
      t[k]     = fminf(fmaxf(rintf(v0[k] * scale), -1.f), 1.f);
      t[4 + k] = fminf(fmaxf(rintf(v1[k] * scale), -1.f), 1.f);
    }
    u32x2 o;
    o[0] = pack4(t[0], t[1], t[2], t[3]);
    o[1] = pack4(t[4], t[5], t[6], t[7]);
    ((u32x2*)tern)[i] = o;
  }
}

// ---------------- RMSNorm + per-token int8 absmax quant (H=2048) ----------------
__global__ __launch_bounds__(256) void actq1_kernel(const float* __restrict__ x,
                                                    const float* __restrict__ g,
                                                    signed char* __restrict__ q,
                                                    float* __restrict__ a) {
  int t = blockIdx.x, tid = threadIdx.x;
  int lane = tid & 63, wv = tid >> 6;
  __shared__ float redS[4], redM[4];

  const f32x4* xr = (const f32x4*)(x + (size_t)t * 2048);
  f32x4 v0 = xr[tid * 2], v1 = xr[tid * 2 + 1];
  float ssq = 0.f;
  #pragma unroll
  for (int k = 0; k < 4; k++) ssq += v0[k] * v0[k] + v1[k] * v1[k];
  float ws_ = wave_sum(ssq);
  if (lane == 0) redS[wv] = ws_;
  __syncthreads();
  float tot = redS[0] + redS[1] + redS[2] + redS[3];
  float r = rsqrtf(tot / 2048.f + 1e-8f);

  f32x4 g0 = ((const f32x4*)g)[tid * 2], g1 = ((const f32x4*)g)[tid * 2 + 1];
  float h[8], amax = 0.f;
  #pragma unroll
  for (int k = 0; k < 4; k++) {
    h[k]     = v0[k] * r * g0[k];
    h[4 + k] = v1[k] * r * g1[k];
    amax = fmaxf(amax, fmaxf(fabsf(h[k]), fabsf(h[4 + k])));
  }
  float wm = wave_max(amax);
  if (lane == 0) redM[wv] = wm;
  __syncthreads();
  float am = fmaxf(fmaxf(fmaxf(redM[0], redM[1]), fmaxf(redM[2], redM[3])), 1e-5f);
  float scale = 127.f / am;

  float qv[8];
  #pragma unroll
  for (int k = 0; k < 8; k++) qv[k] = fminf(fmaxf(rintf(h[k] * scale), -128.f), 127.f);
  u32x2 o;
  o[0] = pack4(qv[0], qv[1], qv[2], qv[3]);
  o[1] = pack4(qv[4], qv[5], qv[6], qv[7]);
  ((u32x2*)(q + (size_t)t * 2048))[tid] = o;
  if (tid == 0) a[t] = am / 127.f;
}

// ---------------- SiLU(gate)*up + RMSNorm + quant (I=8192); y fp16 [T,16384] ----------------
__global__ __launch_bounds__(256) void silu_rms_q_kernel(const unsigned short* __restrict__ y,
                                                         const float* __restrict__ g,
                                                         signed char* __restrict__ q2,
                                                         float* __restrict__ a2) {
  int t = blockIdx.x, tid = threadIdx.x;
  int lane = tid & 63, wv = tid >> 6;
  __shared__ float redS[4], redM[4];
  const u32x4* gate = (const u32x4*)(y + (size_t)t * 16384);
  const u32x4* up   = (const u32x4*)(y + (size_t)t * 16384 + 8192);

  float v[32];
  float ssq = 0.f;
  #pragma unroll
  for (int b = 0; b < 4; b++) {
    u32x4 gr = gate[b * 256 + tid];
    u32x4 ur = up[b * 256 + tid];
    #pragma unroll
    for (int k = 0; k < 4; k++) {
      float g0 = __half2float(__ushort_as_half((unsigned short)(gr[k] & 0xFFFFu)));
      float g1 = __half2float(__ushort_as_half((unsigned short)(gr[k] >> 16)));
      float u0 = __half2float(__ushort_as_half((unsigned short)(ur[k] & 0xFFFFu)));
      float u1 = __half2float(__ushort_as_half((unsigned short)(ur[k] >> 16)));
      float v0 = g0 / (1.f + expf(-g0)) * u0;
      float v1 = g1 / (1.f + expf(-g1)) * u1;
      v[b * 8 + 2 * k] = v0;
      v[b * 8 + 2 * k + 1] = v1;
      ssq += v0 * v0 + v1 * v1;
    }
  }
  float ws_ = wave_sum(ssq);
  if (lane == 0) redS[wv] = ws_;
  __syncthreads();
  float tot = redS[0] + redS[1] + redS[2] + redS[3];
  float r = rsqrtf(tot / 8192.f + 1e-8f);

  float amax = 0.f;
  #pragma unroll
  for (int b = 0; b < 4; b++) {
    f32x4 ga = ((const f32x4*)g)[b * 512 + tid * 2];
    f32x4 gb = ((const f32x4*)g)[b * 512 + tid * 2 + 1];
    #pragma unroll
    for (int k = 0; k < 4; k++) {
      float h0 = v[b * 8 + k]     * r * ga[k];
      float h1 = v[b * 8 + 4 + k] * r * gb[k];
      v[b * 8 + k] = h0;
      v[b * 8 + 4 + k] = h1;
      amax = fmaxf(amax, fmaxf(fabsf(h0), fabsf(h1)));
    }
  }
  float wm = wave_max(amax);
  if (lane == 0) redM[wv] = wm;
  __syncthreads();
  float am = fmaxf(fmaxf(fmaxf(redM[0], redM[1]), fmaxf(redM[2], redM[3])), 1e-5f);
  float scale = 127.f / am;

  #pragma unroll
  for (int b = 0; b < 4; b++) {
    float qv[8];
    #pragma unroll
    for (int k = 0; k < 8; k++)
      qv[k] = fminf(fmaxf(rintf(v[b * 8 + k] * scale), -128.f), 127.f);
    u32x2 o;
    o[0] = pack4(qv[0], qv[1], qv[2], qv[3]);
    o[1] = pack4(qv[4], qv[5], qv[6], qv[7]);
    ((u32x2*)(q2 + (size_t)t * 8192))[b * 256 + tid] = o;
  }
  if (tid == 0) a2[t] = am / 127.f;
}

// ================= shared GEMM machinery =================
// T2 involution (verified r2, PMC conflicts = 0): LDS[rr][chunk c] = global[rr][c ^ (rr&7)]
// (16B chunks, 128B rows); read chunk for (ks,qq) at ((ks<<2)|qq) ^ (fr&7).
// Schedule (r3/r4): ONE s_barrier + ONE vmcnt(0) per K-tile; ALL staging for t+1 issued at
// the TOP of tile t (dest buffer was fully consumed in tile t-1) -> boundary vmcnt(0) waits
// on ~full-tile-old loads, zero exposed HBM latency.
// r4 wave-stagger: odd waves process ks1 clusters before ks0 (same stable buffer; acc order
// irrelevant). Breaks CU-wide phase alignment so MFMA pipe and LDS pipe overlap instead of
// alternating (r3 measured: tile time ~ sum of pipes, not max -> lockstep waves).

#define RD16(P, off) (*(const i32x4*)((P) + (off)))
#define MFMA_I8(a, b, c) __builtin_amdgcn_mfma_i32_16x16x64_i8((a), (b), (c), 0, 0, 0)
#define VM0 asm volatile("s_waitcnt vmcnt(0)" ::: "memory");

#define CB(ks) ((((ks) << 6) | sq) ^ sfx)
#define RDA(d0_, d1_, d2_, d3_, h, ks) { const int o_ = arow0 + (h) * 8192 + CB(ks); \
  d0_ = RD16(Ac, o_); d1_ = RD16(Ac, o_ + 2048); d2_ = RD16(Ac, o_ + 4096); d3_ = RD16(Ac, o_ + 6144); }
#define RDB(d0_, d1_, d2_, d3_, ks) { const int o_ = brow0 + CB(ks); \
  d0_ = RD16(Bc, o_); d1_ = RD16(Bc, o_ + 2048); d2_ = RD16(Bc, o_ + 4096); d3_ = RD16(Bc, o_ + 6144); }

#define CL(h, A0_, A1_, A2_, A3_, B0_, B1_, B2_, B3_) \
  __builtin_amdgcn_s_setprio(1); \
  acc[(h)*4+0][0] = MFMA_I8(A0_, B0_, acc[(h)*4+0][0]); \
  acc[(h)*4+0][1] = MFMA_I8(A0_, B1_, acc[(h)*4+0][1]); \
  acc[(h)*4+0][2] = MFMA_I8(A0_, B2_, acc[(h)*4+0][2]); \
  acc[(h)*4+0][3] = MFMA_I8(A0_, B3_, acc[(h)*4+0][3]); \
  acc[(h)*4+1][0] = MFMA_I8(A1_, B0_, acc[(h)*4+1][0]); \
  acc[(h)*4+1][1] = MFMA_I8(A1_, B1_, acc[(h)*4+1][1]); \
  acc[(h)*4+1][2] = MFMA_I8(A1_, B2_, acc[(h)*4+1][2]); \
  acc[(h)*4+1][3] = MFMA_I8(A1_, B3_, acc[(h)*4+1][3]); \
  acc[(h)*4+2][0] = MFMA_I8(A2_, B0_, acc[(h)*4+2][0]); \
  acc[(h)*4+2][1] = MFMA_I8(A2_, B1_, acc[(h)*4+2][1]); \
  acc[(h)*4+2][2] = MFMA_I8(A2_, B2_, acc[(h)*4+2][2]); \
  acc[(h)*4+2][3] = MFMA_I8(A2_, B3_, acc[(h)*4+2][3]); \
  acc[(h)*4+3][0] = MFMA_I8(A3_, B0_, acc[(h)*4+3][0]); \
  acc[(h)*4+3][1] = MFMA_I8(A3_, B1_, acc[(h)*4+3][1]); \
  acc[(h)*4+3][2] = MFMA_I8(A3_, B2_, acc[(h)*4+3][2]); \
  acc[(h)*4+3][3] = MFMA_I8(A3_, B3_, acc[(h)*4+3][3]); \
  __builtin_amdgcn_s_setprio(0);

// 256x256 tile body: 4 clusters of 16 MFMA; KA processed before KB (wave-parity swapped).
// S = staging statements for tile t+1, issued first (max vmcnt cover).
#define TILE_BODY(S, KA, KB) { \
  i32x4 a0, a1, a2, a3, b0, b1, b2, b3, c0, c1, c2, c3, d0, d1, d2, d3; \
  S \
  RDA(a0, a1, a2, a3, 0, KA)             /* A h0,KA */ \
  RDB(b0, b1, b2, b3, KA)                /* B KA */ \
  RDA(c0, c1, c2, c3, 1, KA)             /* A h1,KA */ \
  CL(0, a0, a1, a2, a3, b0, b1, b2, b3) \
  RDA(d0, d1, d2, d3, 0, KB)             /* A h0,KB */ \
  RDB(a0, a1, a2, a3, KB)                /* B KB (a* dead) */ \
  CL(1, c0, c1, c2, c3, b0, b1, b2, b3) \
  RDA(b0, b1, b2, b3, 1, KB)             /* A h1,KB (b* dead) */ \
  CL(0, d0, d1, d2, d3, a0, a1, a2, a3) \
  CL(1, b0, b1, b2, b3, a0, a1, a2, a3) \
}

// ================= 256x256 int8 MFMA GEMM (GEMM1) =================
// OUT_MODE: 0 = fp16 (ushort), 1 = fp32 (float)
template <int OUT_MODE>
__global__ __launch_bounds__(512, 2) void gemm256_i8_kernel(
    const signed char* __restrict__ A, const signed char* __restrict__ B,
    void* __restrict__ Cv, int M, int N, int K,
    const float* __restrict__ rowscale, const double* __restrict__ wsum, double inv_n) {
  __shared__ __align__(16) signed char lds[131072];
  const int tid = threadIdx.x;
  const int lane = tid & 63;
  const int wid = tid >> 6;
  const int wr = wid >> 2;   // 0..1 -> 128 output rows each
  const int wc = wid & 3;    // 0..3 -> 64 output cols each

  // T1: XCD-aware block swizzle (gridDim.x % 8 == 0)
  const int nbn = N >> 8;
  const int b = blockIdx.x;
  const int cpx = gridDim.x >> 3;
  const int sb = (b & 7) * cpx + (b >> 3);
  const int m0 = (sb / nbn) << 8;
  const int n0 = (sb % nbn) << 8;

  const int fr = lane & 15;            // row within 16-row frag
  const int sq = (lane >> 4) << 4;     // qq*16 (16B K-chunk)
  const int sfx = (fr & 7) << 4;       // swizzle XOR term
  const int arow0 = (wr * 128 + fr) * 128;
  const int brow0 = (wc * 64 + fr) * 128;

  // staging source (swizzle pre-applied to global column; LDS dest stays linear)
  const int rr = tid >> 3;                         // row within 64-row group
  const int co = (((tid & 7) ^ (rr & 7)) << 4);    // swizzled source column
  const signed char* gA = A + (size_t)(m0 + rr) * K + co;
  const signed char* gB = B + (size_t)(n0 + rr) * K + co;
  const size_t g64 = (size_t)64 * K;

  i32x4 acc[8][4] = {};
  const int NT = K >> 7;

  // prologue: stage all 8 groups of tile 0 into buf0
  {
    signed char* Ad = lds + tid * 16;
    signed char* Bd = Ad + 32768;
    gload16(gB,           Bd);
    gload16(gB + g64,     Bd + 8192);
    gload16(gB + 2 * g64, Bd + 16384);
    gload16(gB + 3 * g64, Bd + 24576);
    gload16(gA,           Ad);
    gload16(gA + g64,     Ad + 8192);
    gload16(gA + 2 * g64, Ad + 16384);
    gload16(gA + 3 * g64, Ad + 24576);
    VM0
    __builtin_amdgcn_s_barrier();
  }

#define STAGE_ALL \
    gload16(gBt, Bd); gload16(gBt + g64, Bd + 8192); \
    gload16(gBt + 2 * g64, Bd + 16384); gload16(gBt + 3 * g64, Bd + 24576); \
    gload16(gAt, Ad); gload16(gAt + g64, Ad + 8192); \
    gload16(gAt + 2 * g64, Ad + 16384); gload16(gAt + 3 * g64, Ad + 24576);

  for (int t = 0; t < NT - 1; ++t) {
    const signed char* Ac = lds + ((t & 1) << 16);
    const signed char* Bc = Ac + 32768;
    signed char* Ad = lds + (((t & 1) ^ 1) << 16) + tid * 16;
    signed char* Bd = Ad + 32768;
    const signed char* gAt = gA + (size_t)(t + 1) * 128;
    const signed char* gBt = gB + (size_t)(t + 1) * 128;

    if (wid & 1) { TILE_BODY(STAGE_ALL, 1, 0) }
    else         { TILE_BODY(STAGE_ALL, 0, 1) }

    VM0                              // loads issued a full tile ago -> ~free
    __builtin_amdgcn_s_barrier();    // all 8 groups of tile t+1 visible to all waves
  }

  // tail tile: no staging
  {
    const signed char* Ac = lds + (((NT - 1) & 1) << 16);
    const signed char* Bc = Ac + 32768;
    if (wid & 1) { TILE_BODY(, 1, 0) }
    else         { TILE_BODY(, 0, 1) }
  }

  // epilogue: C/D map col = lane&15, row = (lane>>4)*4 + reg (verified layout)
  float sw = (float)fmax(*wsum * inv_n, 1e-5);
  const int qo = lane >> 4;
  const int cb = n0 + wc * 64 + fr;
  #pragma unroll
  for (int ai = 0; ai < 8; ai++) {
    const int rowb = m0 + wr * 128 + ai * 16 + qo * 4;
    #pragma unroll
    for (int r = 0; r < 4; r++) {
      float sc = rowscale[rowb + r] * sw;
      size_t off = (size_t)(rowb + r) * N + cb;
      #pragma unroll
      for (int n = 0; n < 4; n++) {
        float vv = (float)acc[ai][n][r] * sc;
        if (OUT_MODE == 0) ((unsigned short*)Cv)[off + n * 16] = __half_as_ushort(__float2half(vv));
        else               ((float*)Cv)[off + n * 16] = vv;
      }
    }
  }
}

// ================= 128x256 int8 MFMA GEMM (GEMM2: M=4096,N=2048 -> 256 blocks) =================
// Same swizzle/schedule; wave tile 64x64, acc[4][4]; LDS (A 16K + B 32K) x 2 = 96 KiB.
#define CL16(AA0, AA1, AA2, AA3, B0_, B1_, B2_, B3_) \
  __builtin_amdgcn_s_setprio(1); \
  acc[0][0] = MFMA_I8(AA0, B0_, acc[0][0]); \
  acc[0][1] = MFMA_I8(AA0, B1_, acc[0][1]); \
  acc[0][2] = MFMA_I8(AA0, B2_, acc[0][2]); \
  acc[0][3] = MFMA_I8(AA0, B3_, acc[0][3]); \
  acc[1][0] = MFMA_I8(AA1, B0_, acc[1][0]); \
  acc[1][1] = MFMA_I8(AA1, B1_, acc[1][1]); \
  acc[1][2] = MFMA_I8(AA1, B2_, acc[1][2]); \
  acc[1][3] = MFMA_I8(AA1, B3_, acc[1][3]); \
  acc[2][0] = MFMA_I8(AA2, B0_, acc[2][0]); \
  acc[2][1] = MFMA_I8(AA2, B1_, acc[2][1]); \
  acc[2][2] = MFMA_I8(AA2, B2_, acc[2][2]); \
  acc[2][3] = MFMA_I8(AA2, B3_, acc[2][3]); \
  acc[3][0] = MFMA_I8(AA3, B0_, acc[3][0]); \
  acc[3][1] = MFMA_I8(AA3, B1_, acc[3][1]); \
  acc[3][2] = MFMA_I8(AA3, B2_, acc[3][2]); \
  acc[3][3] = MFMA_I8(AA3, B3_, acc[3][3]); \
  __builtin_amdgcn_s_setprio(0);

#define RDA2(d0_, d1_, d2_, d3_, ks) { const int o_ = arow0 + CB(ks); \
  d0_ = RD16(Ac, o_); d1_ = RD16(Ac, o_ + 2048); d2_ = RD16(Ac, o_ + 4096); d3_ = RD16(Ac, o_ + 6144); }

#define TILE_BODY2(S, KA, KB) { \
  i32x4 a0, a1, a2, a3, b0, b1, b2, b3, c0, c1, c2, c3, d0, d1, d2, d3; \
  S \
  RDA2(a0, a1, a2, a3, KA)  RDB(b0, b1, b2, b3, KA) \
  RDA2(c0, c1, c2, c3, KB) \
  CL16(a0, a1, a2, a3, b0, b1, b2, b3) \
  RDB(d0, d1, d2, d3, KB) \
  CL16(c0, c1, c2, c3, d0, d1, d2, d3) \
}

template <int OUT_MODE>
__global__ __launch_bounds__(512, 1) void gemm128_i8_kernel(
    const signed char* __restrict__ A, const signed char* __restrict__ B,
    void* __restrict__ Cv, int M, int N, int K,
    const float* __restrict__ rowscale, const double* __restrict__ wsum, double inv_n) {
  __shared__ __align__(16) signed char lds[98304];
  const int tid = threadIdx.x;
  const int lane = tid & 63;
  const int wid = tid >> 6;
  const int wr = wid >> 2;   // 0..1 -> 64 output rows each
  const int wc = wid & 3;    // 0..3 -> 64 output cols each

  const int nbn = N >> 8;                 // 8 col tiles
  const int b = blockIdx.x;
  const int cpx = gridDim.x >> 3;
  const int sb = (b & 7) * cpx + (b >> 3);
  const int m0 = (sb / nbn) << 7;         // BM=128
  const int n0 = (sb % nbn) << 8;

  const int fr = lane & 15;
  const int sq = (lane >> 4) << 4;
  const int sfx = (fr & 7) << 4;
  const int arow0 = (wr * 64 + fr) * 128;
  const int brow0 = (wc * 64 + fr) * 128;

  const int rr = tid >> 3;
  const int co = (((tid & 7) ^ (rr & 7)) << 4);
  const signed char* gA = A + (size_t)(m0 + rr) * K + co;
  const signed char* gB = B + (size_t)(n0 + rr) * K + co;
  const size_t g64 = (size_t)64 * K;

  i32x4 acc[4][4] = {};
  const int NT = K >> 7;

  // prologue: tile 0 -> buf0 (A: 2 groups of 64 rows; B: 4 groups)
  {
    signed char* Ad = lds + tid * 16;
    signed char* Bd = Ad + 16384;
    gload16(gB,           Bd);
    gload16(gB + g64,     Bd + 8192);
    gload16(gB + 2 * g64, Bd + 16384);
    gload16(gB + 3 * g64, Bd + 24576);
    gload16(gA,           Ad);
    gload16(gA + g64,     Ad + 8192);
    VM0
    __builtin_amdgcn_s_barrier();
  }

#define STAGE_ALL2 \
    gload16(gBt, Bd); gload16(gBt + g64, Bd + 8192); \
    gload16(gBt + 2 * g64, Bd + 16384); gload16(gBt + 3 * g64, Bd + 24576); \
    gload16(gAt, Ad); gload16(gAt + g64, Ad + 8192);

  for (int t = 0; t < NT - 1; ++t) {
    const signed char* Ac = lds + (t & 1) * 49152;
    const signed char* Bc = Ac + 16384;
    signed char* Ad = lds + ((t & 1) ^ 1) * 49152 + tid * 16;
    signed char* Bd = Ad + 16384;
    const signed char* gAt = gA + (size_t)(t + 1) * 128;
    const signed char* gBt = gB + (size_t)(t + 1) * 128;

    if (wid & 1) { TILE_BODY2(STAGE_ALL2, 1, 0) }
    else         { TILE_BODY2(STAGE_ALL2, 0, 1) }

    VM0
    __builtin_amdgcn_s_barrier();
  }

  {
    const signed char* Ac = lds + ((NT - 1) & 1) * 49152;
    const signed char* Bc = Ac + 16384;
    if (wid & 1) { TILE_BODY2(, 1, 0) }
    else         { TILE_BODY2(, 0, 1) }
  }

  float sw = (float)fmax(*wsum * inv_n, 1e-5);
  const int qo = lane >> 4;
  const int cb = n0 + wc * 64 + fr;
  #pragma unroll
  for (int ai = 0; ai < 4; ai++) {
    const int rowb = m0 + wr * 64 + ai * 16 + qo * 4;
    #pragma unroll
    for (int r = 0; r < 4; r++) {
      float sc = rowscale[rowb + r] * sw;
      size_t off = (size_t)(rowb + r) * N + cb;
      #pragma unroll
      for (int n = 0; n < 4; n++) {
        float vv = (float)acc[ai][n][r] * sc;
        if (OUT_MODE == 0) ((unsigned short*)Cv)[off + n * 16] = __half_as_ushort(__float2half(vv));
        else               ((float*)Cv)[off + n * 16] = vv;
      }
    }
  }
}

extern "C" void kernel_launch(void* const* d_in, const int* in_sizes, int n_in,
                              void* d_out, int out_size, void* d_ws, size_t ws_size,
                              hipStream_t stream) {
  const float* x      = (const float*)d_in[0];
  const float* w_gate = (const float*)d_in[1];
  const float* g_gate = (const float*)d_in[2];
  const float* w_down = (const float*)d_in[3];
  const float* g_down = (const float*)d_in[4];
  float* out = (float*)d_out;

  char* ws = (char*)d_ws;
  double* sums = (double*)ws;                                    // 2 doubles
  float* a1 = (float*)(ws + 4096);                               // 4096 f32
  float* a2 = (float*)(ws + 20480);                              // 4096 f32
  const size_t MB = 1024 * 1024;
  signed char* tern_g = (signed char*)(ws + 65536);              // 16384x2048 i8 = 32 MiB
  signed char* q2     = tern_g;                                  // alias: tern_g dead after GEMM1 (32 MiB)
  signed char* tern_d = (signed char*)(ws + 65536 + 32 * MB);    // 2048x8192 i8 = 16 MiB
  signed char* q1     = (signed char*)(ws + 65536 + 48 * MB);    // 4096x2048 i8 = 8 MiB
  unsigned short* yh  = (unsigned short*)(ws + 65536 + 56 * MB); // 4096x16384 fp16 = 128 MiB

  hipMemsetAsync(sums, 0, 16, stream);
  absum_kernel<<<2048, 256, 0, stream>>>(w_gate, 33554432LL / 4, sums + 0);
  absum_kernel<<<1024, 256, 0, stream>>>(w_down, 16777216LL / 4, sums + 1);
  quantw_kernel<<<4096, 256, 0, stream>>>(w_gate, tern_g, 33554432LL / 8, sums + 0, 1.0 / 33554432.0);
  quantw_kernel<<<2048, 256, 0, stream>>>(w_down, tern_d, 16777216LL / 8, sums + 1, 1.0 / 16777216.0);
  actq1_kernel<<<4096, 256, 0, stream>>>(x, g_gate, q1, a1);
  // GEMM1: M=4096, N=16384, K=2048 -> 1024 blocks of 256x256
  gemm256_i8_kernel<0><<<1024, 512, 0, stream>>>(q1, tern_g, yh, 4096, 16384, 2048,
                                                 a1, sums + 0, 1.0 / 33554432.0);
  silu_rms_q_kernel<<<4096, 256, 0, stream>>>(yh, g_down, q2, a2);
  // GEMM2: M=4096, N=2048, K=8192 -> 256 blocks of 128x256 (full CU coverage)
  gemm128_i8_kernel<1><<<256, 512, 0, stream>>>(q2, tern_d, out, 4096, 2048, 8192,
                                                a2, sums + 1, 1.0 / 16777216.0);
}

// Round 6
// 562.297 us; speedup vs baseline: 1.1794x; 1.0524x over previous
//
#include <hip/hip_runtime.h>
#include <hip/hip_bf16.h>
#include <hip/hip_fp16.h>

#define DEVINL __device__ __forceinline__

typedef float f32x4 __attribute__((ext_vector_type(4)));
typedef int i32x4 __attribute__((ext_vector_type(4)));
typedef unsigned int u32x4 __attribute__((ext_vector_type(4)));
typedef unsigned int u32x2 __attribute__((ext_vector_type(2)));

typedef __attribute__((address_space(1))) void void_g;
typedef __attribute__((address_space(3))) void void_l;

DEVINL void gload16(const void* g, void* l) {
  // async global->LDS, 16B/lane; LDS dst must be wave-uniform base + lane*16
  __builtin_amdgcn_global_load_lds((void_g*)g, (void_l*)l, 16, 0, 0);
}

DEVINL float wave_sum(float v) {
  #pragma unroll
  for (int o = 32; o > 0; o >>= 1) v += __shfl_down(v, o, 64);
  return v;
}
DEVINL float wave_max(float v) {
  #pragma unroll
  for (int o = 32; o > 0; o >>= 1) v = fmaxf(v, __shfl_down(v, o, 64));
  return v;
}

// pack 4 already-rounded-and-clamped floats into 4 signed bytes
DEVINL unsigned int pack4(float a, float b, float c, float d) {
  return ((unsigned int)(unsigned char)(signed char)(int)a)
       | (((unsigned int)(unsigned char)(signed char)(int)b) << 8)
       | (((unsigned int)(unsigned char)(signed char)(int)c) << 16)
       | (((unsigned int)(unsigned char)(signed char)(int)d) << 24);
}

// ---------------- sum(|w|) over fp32 tensor -> double ----------------
__global__ __launch_bounds__(256) void absum_kernel(const float* __restrict__ w,
                                                    long long nchunk, double* __restrict__ out) {
  long long stride = (long long)gridDim.x * 256;
  long long i = (long long)blockIdx.x * 256 + threadIdx.x;
  float s = 0.f;
  for (; i < nchunk; i += stride) {
    f32x4 v = ((const f32x4*)w)[i];
    s += fabsf(v[0]) + fabsf(v[1]) + fabsf(v[2]) + fabsf(v[3]);
  }
  s = wave_sum(s);
  __shared__ float red[4];
  int lane = threadIdx.x & 63, wv = threadIdx.x >> 6;
  if (lane == 0) red[wv] = s;
  __syncthreads();
  if (threadIdx.x == 0) atomicAdd(out, (double)(red[0] + red[1] + red[2] + red[3]));
}

// ---------------- ternary weight quant -> int8 {-1,0,1} ----------------
__global__ __launch_bounds__(256) void quantw_kernel(const float* __restrict__ w,
                                                     signed char* __restrict__ tern,
                                                     long long nchunk,  // groups of 8 floats
                                                     const double* __restrict__ sum, double inv_n) {
  float scale = (float)(1.0 / fmax(*sum * inv_n, 1e-5));
  long long stride = (long long)gridDim.x * 256;
  long long i = (long long)blockIdx.x * 256 + threadIdx.x;
  for (; i < nchunk; i += stride) {
    f32x4 v0 = ((const f32x4*)w)[2 * i];
    f32x4 v1 = ((const f32x4*)w)[2 * i + 1];
    float t[8];
    #pragma unroll
    for (int k = 0; k < 4; k++) {
      t[k]     = fminf(fmaxf(rintf(v0[k] * scale), -1.f), 1.f);
      t[4 + k] = fminf(fmaxf(rintf(v1[k] * scale), -1.f), 1.f);
    }
    u32x2 o;
    o[0] = pack4(t[0], t[1], t[2], t[3]);
    o[1] = pack4(t[4], t[5], t[6], t[7]);
    ((u32x2*)tern)[i] = o;
  }
}

// ---------------- RMSNorm + per-token int8 absmax quant (H=2048) ----------------
__global__ __launch_bounds__(256) void actq1_kernel(const float* __restrict__ x,
                                                    const float* __restrict__ g,
                                                    signed char* __restrict__ q,
                                                    float* __restrict__ a) {
  int t = blockIdx.x, tid = threadIdx.x;
  int lane = tid & 63, wv = tid >> 6;
  __shared__ float redS[4], redM[4];

  const f32x4* xr = (const f32x4*)(x + (size_t)t * 2048);
  f32x4 v0 = xr[tid * 2], v1 = xr[tid * 2 + 1];
  float ssq = 0.f;
  #pragma unroll
  for (int k = 0; k < 4; k++) ssq += v0[k] * v0[k] + v1[k] * v1[k];
  float ws_ = wave_sum(ssq);
  if (lane == 0) redS[wv] = ws_;
  __syncthreads();
  float tot = redS[0] + redS[1] + redS[2] + redS[3];
  float r = rsqrtf(tot / 2048.f + 1e-8f);

  f32x4 g0 = ((const f32x4*)g)[tid * 2], g1 = ((const f32x4*)g)[tid * 2 + 1];
  float h[8], amax = 0.f;
  #pragma unroll
  for (int k = 0; k < 4; k++) {
    h[k]     = v0[k] * r * g0[k];
    h[4 + k] = v1[k] * r * g1[k];
    amax = fmaxf(amax, fmaxf(fabsf(h[k]), fabsf(h[4 + k])));
  }
  float wm = wave_max(amax);
  if (lane == 0) redM[wv] = wm;
  __syncthreads();
  float am = fmaxf(fmaxf(fmaxf(redM[0], redM[1]), fmaxf(redM[2], redM[3])), 1e-5f);
  float scale = 127.f / am;

  float qv[8];
  #pragma unroll
  for (int k = 0; k < 8; k++) qv[k] = fminf(fmaxf(rintf(h[k] * scale), -128.f), 127.f);
  u32x2 o;
  o[0] = pack4(qv[0], qv[1], qv[2], qv[3]);
  o[1] = pack4(qv[4], qv[5], qv[6], qv[7]);
  ((u32x2*)(q + (size_t)t * 2048))[tid] = o;
  if (tid == 0) a[t] = am / 127.f;
}

// ---------------- SiLU(gate)*up + RMSNorm + quant (I=8192); y fp16 [T,16384] ----------------
__global__ __launch_bounds__(256) void silu_rms_q_kernel(const unsigned short* __restrict__ y,
                                                         const float* __restrict__ g,
                                                         signed char* __restrict__ q2,
                                                         float* __restrict__ a2) {
  int t = blockIdx.x, tid = threadIdx.x;
  int lane = tid & 63, wv = tid >> 6;
  __shared__ float redS[4], redM[4];
  const u32x4* gate = (const u32x4*)(y + (size_t)t * 16384);
  const u32x4* up   = (const u32x4*)(y + (size_t)t * 16384 + 8192);

  float v[32];
  float ssq = 0.f;
  #pragma unroll
  for (int b = 0; b < 4; b++) {
    u32x4 gr = gate[b * 256 + tid];
    u32x4 ur = up[b * 256 + tid];
    #pragma unroll
    for (int k = 0; k < 4; k++) {
      float g0 = __half2float(__ushort_as_half((unsigned short)(gr[k] & 0xFFFFu)));
      float g1 = __half2float(__ushort_as_half((unsigned short)(gr[k] >> 16)));
      float u0 = __half2float(__ushort_as_half((unsigned short)(ur[k] & 0xFFFFu)));
      float u1 = __half2float(__ushort_as_half((unsigned short)(ur[k] >> 16)));
      float v0 = g0 / (1.f + expf(-g0)) * u0;
      float v1 = g1 / (1.f + expf(-g1)) * u1;
      v[b * 8 + 2 * k] = v0;
      v[b * 8 + 2 * k + 1] = v1;
      ssq += v0 * v0 + v1 * v1;
    }
  }
  float ws_ = wave_sum(ssq);
  if (lane == 0) redS[wv] = ws_;
  __syncthreads();
  float tot = redS[0] + redS[1] + redS[2] + redS[3];
  float r = rsqrtf(tot / 8192.f + 1e-8f);

  float amax = 0.f;
  #pragma unroll
  for (int b = 0; b < 4; b++) {
    f32x4 ga = ((const f32x4*)g)[b * 512 + tid * 2];
    f32x4 gb = ((const f32x4*)g)[b * 512 + tid * 2 + 1];
    #pragma unroll
    for (int k = 0; k < 4; k++) {
      float h0 = v[b * 8 + k]     * r * ga[k];
      float h1 = v[b * 8 + 4 + k] * r * gb[k];
      v[b * 8 + k] = h0;
      v[b * 8 + 4 + k] = h1;
      amax = fmaxf(amax, fmaxf(fabsf(h0), fabsf(h1)));
    }
  }
  float wm = wave_max(amax);
  if (lane == 0) redM[wv] = wm;
  __syncthreads();
  float am = fmaxf(fmaxf(fmaxf(redM[0], redM[1]), fmaxf(redM[2], redM[3])), 1e-5f);
  float scale = 127.f / am;

  #pragma unroll
  for (int b = 0; b < 4; b++) {
    float qv[8];
    #pragma unroll
    for (int k = 0; k < 8; k++)
      qv[k] = fminf(fmaxf(rintf(v[b * 8 + k] * scale), -128.f), 127.f);
    u32x2 o;
    o[0] = pack4(qv[0], qv[1], qv[2], qv[3]);
    o[1] = pack4(qv[4], qv[5], qv[6], qv[7]);
    ((u32x2*)(q2 + (size_t)t * 8192))[b * 256 + tid] = o;
  }
  if (tid == 0) a2[t] = am / 127.f;
}

// ================= shared GEMM machinery =================
// T2 involution (verified r2, PMC conflicts = 0): LDS[rr][chunk c] = global[rr][c ^ (rr&7)]
// (16B chunks, 128B rows); read chunk for (ks,qq) at ((ks<<2)|qq) ^ (fr&7).
// Schedule: ONE s_barrier + ONE vmcnt(0) per K-tile; ALL staging for t+1 issued at the TOP
// of tile t (dest buffer fully consumed in tile t-1; waves crossing the t-1 barrier have
// finished reading it) -> boundary vmcnt(0) waits on ~full-tile-old loads.
// r5 lesson (spill!): do NOT duplicate the tile body behind wave-parity branches — VGPR
// 116->128 + 43MB scratch WRITE_SIZE + 21MB scratch FETCH, GEMM1 143->160us. Single body.

#define RD16(P, off) (*(const i32x4*)((P) + (off)))
#define MFMA_I8(a, b, c) __builtin_amdgcn_mfma_i32_16x16x64_i8((a), (b), (c), 0, 0, 0)
#define VM0 asm volatile("s_waitcnt vmcnt(0)" ::: "memory");

#define CB(ks) ((((ks) << 6) | sq) ^ sfx)
#define RDA(d0_, d1_, d2_, d3_, h, ks) { const int o_ = arow0 + (h) * 8192 + CB(ks); \
  d0_ = RD16(Ac, o_); d1_ = RD16(Ac, o_ + 2048); d2_ = RD16(Ac, o_ + 4096); d3_ = RD16(Ac, o_ + 6144); }
#define RDB(d0_, d1_, d2_, d3_, ks) { const int o_ = brow0 + CB(ks); \
  d0_ = RD16(Bc, o_); d1_ = RD16(Bc, o_ + 2048); d2_ = RD16(Bc, o_ + 4096); d3_ = RD16(Bc, o_ + 6144); }

#define CL(h, A0_, A1_, A2_, A3_, B0_, B1_, B2_, B3_) \
  __builtin_amdgcn_s_setprio(1); \
  acc[(h)*4+0][0] = MFMA_I8(A0_, B0_, acc[(h)*4+0][0]); \
  acc[(h)*4+0][1] = MFMA_I8(A0_, B1_, acc[(h)*4+0][1]); \
  acc[(h)*4+0][2] = MFMA_I8(A0_, B2_, acc[(h)*4+0][2]); \
  acc[(h)*4+0][3] = MFMA_I8(A0_, B3_, acc[(h)*4+0][3]); \
  acc[(h)*4+1][0] = MFMA_I8(A1_, B0_, acc[(h)*4+1][0]); \
  acc[(h)*4+1][1] = MFMA_I8(A1_, B1_, acc[(h)*4+1][1]); \
  acc[(h)*4+1][2] = MFMA_I8(A1_, B2_, acc[(h)*4+1][2]); \
  acc[(h)*4+1][3] = MFMA_I8(A1_, B3_, acc[(h)*4+1][3]); \
  acc[(h)*4+2][0] = MFMA_I8(A2_, B0_, acc[(h)*4+2][0]); \
  acc[(h)*4+2][1] = MFMA_I8(A2_, B1_, acc[(h)*4+2][1]); \
  acc[(h)*4+2][2] = MFMA_I8(A2_, B2_, acc[(h)*4+2][2]); \
  acc[(h)*4+2][3] = MFMA_I8(A2_, B3_, acc[(h)*4+2][3]); \
  acc[(h)*4+3][0] = MFMA_I8(A3_, B0_, acc[(h)*4+3][0]); \
  acc[(h)*4+3][1] = MFMA_I8(A3_, B1_, acc[(h)*4+3][1]); \
  acc[(h)*4+3][2] = MFMA_I8(A3_, B2_, acc[(h)*4+3][2]); \
  acc[(h)*4+3][3] = MFMA_I8(A3_, B3_, acc[(h)*4+3][3]); \
  __builtin_amdgcn_s_setprio(0);

// 256x256 tile body: 4 clusters of 16 MFMA. S = staging for t+1, issued first.
#define TILE_BODY(S) { \
  i32x4 a0, a1, a2, a3, b0, b1, b2, b3, c0, c1, c2, c3, d0, d1, d2, d3; \
  S \
  RDA(a0, a1, a2, a3, 0, 0) \
  RDB(b0, b1, b2, b3, 0) \
  RDA(c0, c1, c2, c3, 1, 0) \
  CL(0, a0, a1, a2, a3, b0, b1, b2, b3) \
  RDA(d0, d1, d2, d3, 0, 1) \
  RDB(a0, a1, a2, a3, 1) \
  CL(1, c0, c1, c2, c3, b0, b1, b2, b3) \
  RDA(b0, b1, b2, b3, 1, 1) \
  CL(0, d0, d1, d2, d3, a0, a1, a2, a3) \
  CL(1, b0, b1, b2, b3, a0, a1, a2, a3) \
}

// ================= 256x256 int8 MFMA GEMM (GEMM1) =================
// OUT_MODE: 0 = fp16 (ushort), 1 = fp32 (float)
template <int OUT_MODE>
__global__ __launch_bounds__(512, 2) void gemm256_i8_kernel(
    const signed char* __restrict__ A, const signed char* __restrict__ B,
    void* __restrict__ Cv, int M, int N, int K,
    const float* __restrict__ rowscale, const double* __restrict__ wsum, double inv_n) {
  __shared__ __align__(16) signed char lds[131072];
  const int tid = threadIdx.x;
  const int lane = tid & 63;
  const int wid = tid >> 6;
  const int wr = wid >> 2;   // 0..1 -> 128 output rows each
  const int wc = wid & 3;    // 0..3 -> 64 output cols each

  // T1: XCD-aware block swizzle (gridDim.x % 8 == 0)
  const int nbn = N >> 8;
  const int b = blockIdx.x;
  const int cpx = gridDim.x >> 3;
  const int sb = (b & 7) * cpx + (b >> 3);
  const int m0 = (sb / nbn) << 8;
  const int n0 = (sb % nbn) << 8;

  const int fr = lane & 15;            // row within 16-row frag
  const int sq = (lane >> 4) << 4;     // qq*16 (16B K-chunk)
  const int sfx = (fr & 7) << 4;       // swizzle XOR term
  const int arow0 = (wr * 128 + fr) * 128;
  const int brow0 = (wc * 64 + fr) * 128;

  // staging source (swizzle pre-applied to global column; LDS dest stays linear)
  const int rr = tid >> 3;                         // row within 64-row group
  const int co = (((tid & 7) ^ (rr & 7)) << 4);    // swizzled source column
  const signed char* gA = A + (size_t)(m0 + rr) * K + co;
  const signed char* gB = B + (size_t)(n0 + rr) * K + co;
  const size_t g64 = (size_t)64 * K;

  i32x4 acc[8][4] = {};
  const int NT = K >> 7;

  // prologue: stage all 8 groups of tile 0 into buf0
  {
    signed char* Ad = lds + tid * 16;
    signed char* Bd = Ad + 32768;
    gload16(gB,           Bd);
    gload16(gB + g64,     Bd + 8192);
    gload16(gB + 2 * g64, Bd + 16384);
    gload16(gB + 3 * g64, Bd + 24576);
    gload16(gA,           Ad);
    gload16(gA + g64,     Ad + 8192);
    gload16(gA + 2 * g64, Ad + 16384);
    gload16(gA + 3 * g64, Ad + 24576);
    VM0
    __builtin_amdgcn_s_barrier();
  }

#define STAGE_ALL \
    gload16(gBt, Bd); gload16(gBt + g64, Bd + 8192); \
    gload16(gBt + 2 * g64, Bd + 16384); gload16(gBt + 3 * g64, Bd + 24576); \
    gload16(gAt, Ad); gload16(gAt + g64, Ad + 8192); \
    gload16(gAt + 2 * g64, Ad + 16384); gload16(gAt + 3 * g64, Ad + 24576);

  for (int t = 0; t < NT - 1; ++t) {
    const signed char* Ac = lds + ((t & 1) << 16);
    const signed char* Bc = Ac + 32768;
    signed char* Ad = lds + (((t & 1) ^ 1) << 16) + tid * 16;
    signed char* Bd = Ad + 32768;
    const signed char* gAt = gA + (size_t)(t + 1) * 128;
    const signed char* gBt = gB + (size_t)(t + 1) * 128;

    TILE_BODY(STAGE_ALL)

    VM0                              // loads issued a full tile ago -> ~free
    __builtin_amdgcn_s_barrier();    // all 8 groups of tile t+1 visible to all waves
  }

  // tail tile: no staging
  {
    const signed char* Ac = lds + (((NT - 1) & 1) << 16);
    const signed char* Bc = Ac + 32768;
    TILE_BODY()
  }

  // epilogue: C/D map col = lane&15, row = (lane>>4)*4 + reg (verified layout)
  float sw = (float)fmax(*wsum * inv_n, 1e-5);
  const int qo = lane >> 4;
  const int cb = n0 + wc * 64 + fr;
  #pragma unroll
  for (int ai = 0; ai < 8; ai++) {
    const int rowb = m0 + wr * 128 + ai * 16 + qo * 4;
    #pragma unroll
    for (int r = 0; r < 4; r++) {
      float sc = rowscale[rowb + r] * sw;
      size_t off = (size_t)(rowb + r) * N + cb;
      #pragma unroll
      for (int n = 0; n < 4; n++) {
        float vv = (float)acc[ai][n][r] * sc;
        if (OUT_MODE == 0) ((unsigned short*)Cv)[off + n * 16] = __half_as_ushort(__float2half(vv));
        else               ((float*)Cv)[off + n * 16] = vv;
      }
    }
  }
}

// ================= 128x128 int8 MFMA GEMM (GEMM2) =================
// 256 threads (4 waves 2x2), wave tile 64x64, BK=128, LDS (A 16K + B 16K) x 2 = 64 KiB
// -> 2 blocks/CU resident (launch_bounds(256,2)). Grid 512 = 2 blocks/CU: the co-resident
// block's MFMA clusters fill this block's read/barrier-drain phases (m114 cross-block
// overlap) — the mechanism the 128KiB-LDS 256^2 kernel cannot use.
#define CL16(AA0, AA1, AA2, AA3, B0_, B1_, B2_, B3_) \
  __builtin_amdgcn_s_setprio(1); \
  acc[0][0] = MFMA_I8(AA0, B0_, acc[0][0]); \
  acc[0][1] = MFMA_I8(AA0, B1_, acc[0][1]); \
  acc[0][2] = MFMA_I8(AA0, B2_, acc[0][2]); \
  acc[0][3] = MFMA_I8(AA0, B3_, acc[0][3]); \
  acc[1][0] = MFMA_I8(AA1, B0_, acc[1][0]); \
  acc[1][1] = MFMA_I8(AA1, B1_, acc[1][1]); \
  acc[1][2] = MFMA_I8(AA1, B2_, acc[1][2]); \
  acc[1][3] = MFMA_I8(AA1, B3_, acc[1][3]); \
  acc[2][0] = MFMA_I8(AA2, B0_, acc[2][0]); \
  acc[2][1] = MFMA_I8(AA2, B1_, acc[2][1]); \
  acc[2][2] = MFMA_I8(AA2, B2_, acc[2][2]); \
  acc[2][3] = MFMA_I8(AA2, B3_, acc[2][3]); \
  acc[3][0] = MFMA_I8(AA3, B0_, acc[3][0]); \
  acc[3][1] = MFMA_I8(AA3, B1_, acc[3][1]); \
  acc[3][2] = MFMA_I8(AA3, B2_, acc[3][2]); \
  acc[3][3] = MFMA_I8(AA3, B3_, acc[3][3]); \
  __builtin_amdgcn_s_setprio(0);

#define RDA2(d0_, d1_, d2_, d3_, ks) { const int o_ = arow0 + CB(ks); \
  d0_ = RD16(Ac, o_); d1_ = RD16(Ac, o_ + 2048); d2_ = RD16(Ac, o_ + 4096); d3_ = RD16(Ac, o_ + 6144); }

#define TILE_BODY2(S) { \
  i32x4 a0, a1, a2, a3, b0, b1, b2, b3, c0, c1, c2, c3, d0, d1, d2, d3; \
  S \
  RDA2(a0, a1, a2, a3, 0)  RDB(b0, b1, b2, b3, 0) \
  RDA2(c0, c1, c2, c3, 1) \
  CL16(a0, a1, a2, a3, b0, b1, b2, b3) \
  RDB(d0, d1, d2, d3, 1) \
  CL16(c0, c1, c2, c3, d0, d1, d2, d3) \
}

template <int OUT_MODE>
__global__ __launch_bounds__(256, 2) void gemm128sq_i8_kernel(
    const signed char* __restrict__ A, const signed char* __restrict__ B,
    void* __restrict__ Cv, int M, int N, int K,
    const float* __restrict__ rowscale, const double* __restrict__ wsum, double inv_n) {
  __shared__ __align__(16) signed char lds[65536];
  const int tid = threadIdx.x;
  const int lane = tid & 63;
  const int wid = tid >> 6;
  const int wr = wid >> 1;   // 0..1 -> 64 output rows each
  const int wc = wid & 1;    // 0..1 -> 64 output cols each

  const int nbn = N >> 7;                 // 16 col tiles
  const int b = blockIdx.x;
  const int cpx = gridDim.x >> 3;
  const int sb = (b & 7) * cpx + (b >> 3);
  const int m0 = (sb / nbn) << 7;         // BM=128
  const int n0 = (sb % nbn) << 7;         // BN=128

  const int fr = lane & 15;
  const int sq = (lane >> 4) << 4;
  const int sfx = (fr & 7) << 4;
  const int arow0 = (wr * 64 + fr) * 128;
  const int brow0 = (wc * 64 + fr) * 128;

  // staging: 256 threads, rr in [0,32); 4 groups of 32 rows per operand
  const int rr = tid >> 3;
  const int co = (((tid & 7) ^ (rr & 7)) << 4);
  const signed char* gA = A + (size_t)(m0 + rr) * K + co;
  const signed char* gB = B + (size_t)(n0 + rr) * K + co;
  const size_t g32 = (size_t)32 * K;

  i32x4 acc[4][4] = {};
  const int NT = K >> 7;

  // prologue: tile 0 -> buf0 (A 16K: 4 groups of 32 rows; B 16K: 4 groups)
  {
    signed char* Ad = lds + tid * 16;
    signed char* Bd = Ad + 16384;
    gload16(gB,           Bd);
    gload16(gB + g32,     Bd + 4096);
    gload16(gB + 2 * g32, Bd + 8192);
    gload16(gB + 3 * g32, Bd + 12288);
    gload16(gA,           Ad);
    gload16(gA + g32,     Ad + 4096);
    gload16(gA + 2 * g32, Ad + 8192);
    gload16(gA + 3 * g32, Ad + 12288);
    VM0
    __builtin_amdgcn_s_barrier();
  }

#define STAGE_ALL2 \
    gload16(gBt, Bd); gload16(gBt + g32, Bd + 4096); \
    gload16(gBt + 2 * g32, Bd + 8192); gload16(gBt + 3 * g32, Bd + 12288); \
    gload16(gAt, Ad); gload16(gAt + g32, Ad + 4096); \
    gload16(gAt + 2 * g32, Ad + 8192); gload16(gAt + 3 * g32, Ad + 12288);

  for (int t = 0; t < NT - 1; ++t) {
    const signed char* Ac = lds + ((t & 1) << 15);
    const signed char* Bc = Ac + 16384;
    signed char* Ad = lds + (((t & 1) ^ 1) << 15) + tid * 16;
    signed char* Bd = Ad + 16384;
    const signed char* gAt = gA + (size_t)(t + 1) * 128;
    const signed char* gBt = gB + (size_t)(t + 1) * 128;

    TILE_BODY2(STAGE_ALL2)

    VM0
    __builtin_amdgcn_s_barrier();
  }

  {
    const signed char* Ac = lds + (((NT - 1) & 1) << 15);
    const signed char* Bc = Ac + 16384;
    TILE_BODY2()
  }

  float sw = (float)fmax(*wsum * inv_n, 1e-5);
  const int qo = lane >> 4;
  const int cb = n0 + wc * 64 + fr;
  #pragma unroll
  for (int ai = 0; ai < 4; ai++) {
    const int rowb = m0 + wr * 64 + ai * 16 + qo * 4;
    #pragma unroll
    for (int r = 0; r < 4; r++) {
      float sc = rowscale[rowb + r] * sw;
      size_t off = (size_t)(rowb + r) * N + cb;
      #pragma unroll
      for (int n = 0; n < 4; n++) {
        float vv = (float)acc[ai][n][r] * sc;
        if (OUT_MODE == 0) ((unsigned short*)Cv)[off + n * 16] = __half_as_ushort(__float2half(vv));
        else               ((float*)Cv)[off + n * 16] = vv;
      }
    }
  }
}

extern "C" void kernel_launch(void* const* d_in, const int* in_sizes, int n_in,
                              void* d_out, int out_size, void* d_ws, size_t ws_size,
                              hipStream_t stream) {
  const float* x      = (const float*)d_in[0];
  const float* w_gate = (const float*)d_in[1];
  const float* g_gate = (const float*)d_in[2];
  const float* w_down = (const float*)d_in[3];
  const float* g_down = (const float*)d_in[4];
  float* out = (float*)d_out;

  char* ws = (char*)d_ws;
  double* sums = (double*)ws;                                    // 2 doubles
  float* a1 = (float*)(ws + 4096);                               // 4096 f32
  float* a2 = (float*)(ws + 20480);                              // 4096 f32
  const size_t MB = 1024 * 1024;
  signed char* tern_g = (signed char*)(ws + 65536);              // 16384x2048 i8 = 32 MiB
  signed char* q2     = tern_g;                                  // alias: tern_g dead after GEMM1 (32 MiB)
  signed char* tern_d = (signed char*)(ws + 65536 + 32 * MB);    // 2048x8192 i8 = 16 MiB
  signed char* q1     = (signed char*)(ws + 65536 + 48 * MB);    // 4096x2048 i8 = 8 MiB
  unsigned short* yh  = (unsigned short*)(ws + 65536 + 56 * MB); // 4096x16384 fp16 = 128 MiB

  hipMemsetAsync(sums, 0, 16, stream);
  absum_kernel<<<2048, 256, 0, stream>>>(w_gate, 33554432LL / 4, sums + 0);
  absum_kernel<<<1024, 256, 0, stream>>>(w_down, 16777216LL / 4, sums + 1);
  quantw_kernel<<<4096, 256, 0, stream>>>(w_gate, tern_g, 33554432LL / 8, sums + 0, 1.0 / 33554432.0);
  quantw_kernel<<<2048, 256, 0, stream>>>(w_down, tern_d, 16777216LL / 8, sums + 1, 1.0 / 16777216.0);
  actq1_kernel<<<4096, 256, 0, stream>>>(x, g_gate, q1, a1);
  // GEMM1: M=4096, N=16384, K=2048 -> 1024 blocks of 256x256
  gemm256_i8_kernel<0><<<1024, 512, 0, stream>>>(q1, tern_g, yh, 4096, 16384, 2048,
                                                 a1, sums + 0, 1.0 / 33554432.0);
  silu_rms_q_kernel<<<4096, 256, 0, stream>>>(yh, g_down, q2, a2);
  // GEMM2: M=4096, N=2048, K=8192 -> 512 blocks of 128x128, 2 blocks/CU
  gemm128sq_i8_kernel<1><<<512, 256, 0, stream>>>(q2, tern_d, out, 4096, 2048, 8192,
                                                  a2, sums + 1, 1.0 / 16777216.0);
}